// Round 1
// baseline (655.080 us; speedup 1.0000x reference)
//
#include <hip/hip_runtime.h>
#include <hip/hip_bf16.h>
#include <math.h>

#define B_ 4
#define M_ 1024
#define NIN 70
#define D_ 256
#define H_ 8
#define L_ 4
#define DFF_ 1024
#define BM_TOT 4096

typedef __hip_bfloat16 bf16;
typedef short short8 __attribute__((ext_vector_type(8)));
typedef float f32x4 __attribute__((ext_vector_type(4)));

// ---------------- single-launch weight convert+transpose ----------------
// All weights -> bf16 [N][K] (row stride = K). QKV packed per layer as [768][256].
__global__ __launch_bounds__(256) void wconv_all(
    const float* __restrict__ Wq, const float* __restrict__ Wk, const float* __restrict__ Wv,
    const float* __restrict__ Wo, const float* __restrict__ uw, const float* __restrict__ dw,
    const float* __restrict__ finw,
    bf16* __restrict__ wqkvt, bf16* __restrict__ wot, bf16* __restrict__ uwt,
    bf16* __restrict__ dwt, bf16* __restrict__ fwt)
{
  __shared__ float T[64][65];
  int idx = blockIdx.x;
  const float* src; bf16* dst; int K, N, k0, n0, rbase, S;
  if (idx < 192) {            // Wq/Wk/Wv -> wqkvt[l][m*256 + n][k]
    int m = idx >> 6; int r = idx & 63; int l = r >> 4; int tt = r & 15;
    int kt = tt >> 2, nt = tt & 3;
    src = (m == 0 ? Wq : (m == 1 ? Wk : Wv)) + (size_t)l * 65536;
    K = 256; N = 256; k0 = kt * 64; n0 = nt * 64;
    dst = wqkvt + (size_t)l * 196608; rbase = m * 256 + nt * 64; S = 256;
  } else if (idx < 256) {     // Wo
    int r = idx - 192; int l = r >> 4; int tt = r & 15; int kt = tt >> 2, nt = tt & 3;
    src = Wo + (size_t)l * 65536; K = 256; N = 256; k0 = kt * 64; n0 = nt * 64;
    dst = wot + (size_t)l * 65536; rbase = nt * 64; S = 256;
  } else if (idx < 512) {     // uw (256 x 1024)
    int r = idx - 256; int l = r >> 6; int tt = r & 63; int kt = tt >> 4, nt = tt & 15;
    src = uw + (size_t)l * 262144; K = 256; N = 1024; k0 = kt * 64; n0 = nt * 64;
    dst = uwt + (size_t)l * 262144; rbase = nt * 64; S = 256;
  } else if (idx < 768) {     // dw (1024 x 256)
    int r = idx - 512; int l = r >> 6; int tt = r & 63; int kt = tt >> 2, nt = tt & 3;
    src = dw + (size_t)l * 262144; K = 1024; N = 256; k0 = kt * 64; n0 = nt * 64;
    dst = dwt + (size_t)l * 262144; rbase = nt * 64; S = 1024;
  } else {                    // finw (256 x 64)
    int kt = idx - 768;
    src = finw; K = 256; N = 64; k0 = kt * 64; n0 = 0;
    dst = fwt; rbase = 0; S = 256;
  }
  int t = threadIdx.x;
  int kl = t >> 2, ns = (t & 3) * 16;
  #pragma unroll
  for (int i = 0; i < 16; i += 4)
    *(float4*)&T[kl][ns + i] = *(const float4*)&src[(size_t)(k0 + kl) * N + n0 + ns + i];
  __syncthreads();
  int nl = t >> 2, ks = (t & 3) * 16;
  __align__(16) bf16 tmp[16];
  #pragma unroll
  for (int i = 0; i < 16; ++i) tmp[i] = __float2bfloat16(T[ks + i][nl]);
  *(uint4*)&dst[(size_t)(rbase + nl) * S + k0 + ks] = *(uint4*)&tmp[0];
  *(uint4*)&dst[(size_t)(rbase + nl) * S + k0 + ks + 8] = *(uint4*)&tmp[8];
}

// ---------------- embedding fused with layer-0 ln1 ----------------
__global__ __launch_bounds__(256) void k_embed_ln(const float* __restrict__ X,
    const float* __restrict__ fW, const float* __restrict__ fb,
    const float* __restrict__ cW, const float* __restrict__ cb,
    const float* __restrict__ lw, const float* __restrict__ lb,
    float* __restrict__ x, bf16* __restrict__ xn)
{
  int bm = blockIdx.x;
  int d = threadIdx.x;
  __shared__ float xr[NIN];
  __shared__ float red[8];
  if (d < NIN) xr[d] = X[bm * NIN + d];
  __syncthreads();
  int f = d & 127;
  float proj = xr[0] * fW[f * 3 + 0] + xr[1] * fW[f * 3 + 1]
             + xr[2] * fW[f * 3 + 2] + fb[f];
  float pe = (d < 128 ? cosf(proj) : sinf(proj)) * 0.17677669529663687f;
  float acc = pe + cb[d];
  #pragma unroll 8
  for (int c = 0; c < 64; ++c)
    acc += xr[6 + c] * cW[c * D_ + d];
  x[bm * D_ + d] = acc;
  // LN over the 256 values (4 waves)
  float s = acc, q = acc * acc;
  #pragma unroll
  for (int off = 32; off; off >>= 1) {
    s += __shfl_xor(s, off, 64);
    q += __shfl_xor(q, off, 64);
  }
  int wave = d >> 6, lane = d & 63;
  if (lane == 0) { red[wave * 2] = s; red[wave * 2 + 1] = q; }
  __syncthreads();
  float ts = red[0] + red[2] + red[4] + red[6];
  float tq = red[1] + red[3] + red[5] + red[7];
  float mu = ts * (1.0f / D_);
  float var = tq * (1.0f / D_) - mu * mu;
  float rstd = rsqrtf(var + 1e-5f);
  xn[bm * D_ + d] = __float2bfloat16((acc - mu) * rstd * lw[d] + lb[d]);
}

// ---------------- MFMA GEMM (reg-prefetch pipelined) ----------------
__global__ __launch_bounds__(256) void mgemm(const bf16* __restrict__ Ab,
    const bf16* __restrict__ Wt, const float* __restrict__ bias,
    const float* __restrict__ Res, float* __restrict__ Cf, bf16* __restrict__ Cb,
    int K, int N, int flags)
{
  __shared__ short As[64][40];
  __shared__ short Bs[64][40];
  int t = threadIdx.x;
  int m0 = blockIdx.y * 64, n0 = blockIdx.x * 64;
  int w = t >> 6, lane = t & 63;
  int srow = t >> 2, sseg = t & 3;
  f32x4 acc[4] = {{0.f,0.f,0.f,0.f},{0.f,0.f,0.f,0.f},{0.f,0.f,0.f,0.f},{0.f,0.f,0.f,0.f}};
  int mf = w * 16 + (lane & 15);
  int kf = (lane >> 4) * 8;
  const bf16* pA = Ab + (size_t)(m0 + srow) * K + sseg * 8;
  const bf16* pB = Wt + (size_t)(n0 + srow) * K + sseg * 8;
  uint4 ra = *(const uint4*)pA;
  uint4 rb = *(const uint4*)pB;
  for (int k0 = 0; k0 < K; k0 += 32) {
    *(uint4*)&As[srow][sseg * 8] = ra;
    *(uint4*)&Bs[srow][sseg * 8] = rb;
    __syncthreads();
    if (k0 + 32 < K) {
      ra = *(const uint4*)(pA + k0 + 32);
      rb = *(const uint4*)(pB + k0 + 32);
    }
    short8 a = *(short8*)&As[mf][kf];
    #pragma unroll
    for (int nt = 0; nt < 4; ++nt) {
      short8 bfr = *(short8*)&Bs[nt * 16 + (lane & 15)][kf];
      acc[nt] = __builtin_amdgcn_mfma_f32_16x16x32_bf16(a, bfr, acc[nt], 0, 0, 0);
    }
    __syncthreads();
  }
  int row0 = m0 + w * 16 + (lane >> 4) * 4;
  #pragma unroll
  for (int nt = 0; nt < 4; ++nt) {
    int col = n0 + nt * 16 + (lane & 15);
    float bs = bias[col];
    #pragma unroll
    for (int r = 0; r < 4; ++r) {
      float v = acc[nt][r] + bs;
      if (flags & 1) v = 0.5f * v * (1.0f + erff(v * 0.70710678118654752f));
      if (flags & 2) v += Res[(size_t)(row0 + r) * N + col];
      if (flags & 8) Cf[(size_t)(row0 + r) * N + col] = v;
      if (flags & 4) Cb[(size_t)(row0 + r) * N + col] = __float2bfloat16(v);
    }
  }
}

// ---------------- full-row MFMA GEMM (N=256) fused with residual + LayerNorm ----------------
// Each block: 64 rows x 256 cols. Epilogue: v = acc + bias + xf; xf = v; LN(v) -> xn (bf16).
// Row LN: C-fragment layout puts a full row in one 16-lane group -> 4 shfl_xor hops.
__global__ __launch_bounds__(256) void mgemm_ln(const bf16* __restrict__ Ab,
    const bf16* __restrict__ Wt, const float* __restrict__ bias,
    const float* __restrict__ lw, const float* __restrict__ lb,
    float* __restrict__ xf, bf16* __restrict__ xn, int K)
{
  __shared__ short As[64][40];
  __shared__ short Bs[256][40];
  int t = threadIdx.x;
  int m0 = blockIdx.x * 64;
  int w = t >> 6, lane = t & 63;
  int srow = t >> 2, sseg = t & 3;
  f32x4 acc[16];
  #pragma unroll
  for (int i = 0; i < 16; ++i) acc[i] = (f32x4){0.f,0.f,0.f,0.f};
  int mf = w * 16 + (lane & 15);
  int kf = (lane >> 4) * 8;
  const bf16* pA = Ab + (size_t)(m0 + srow) * K + sseg * 8;
  const bf16* pB = Wt + (size_t)srow * K + sseg * 8;
  uint4 ra = *(const uint4*)pA;
  uint4 rb[4];
  #pragma unroll
  for (int i = 0; i < 4; ++i) rb[i] = *(const uint4*)(pB + (size_t)(64 * i) * K);
  for (int k0 = 0; k0 < K; k0 += 32) {
    *(uint4*)&As[srow][sseg * 8] = ra;
    #pragma unroll
    for (int i = 0; i < 4; ++i) *(uint4*)&Bs[srow + 64 * i][sseg * 8] = rb[i];
    __syncthreads();
    if (k0 + 32 < K) {
      ra = *(const uint4*)(pA + k0 + 32);
      #pragma unroll
      for (int i = 0; i < 4; ++i)
        rb[i] = *(const uint4*)(pB + (size_t)(64 * i) * K + k0 + 32);
    }
    short8 a = *(short8*)&As[mf][kf];
    #pragma unroll
    for (int nt = 0; nt < 16; ++nt) {
      short8 bfr = *(short8*)&Bs[nt * 16 + (lane & 15)][kf];
      acc[nt] = __builtin_amdgcn_mfma_f32_16x16x32_bf16(a, bfr, acc[nt], 0, 0, 0);
    }
    __syncthreads();
  }
  int row0 = m0 + w * 16 + (lane >> 4) * 4;
  int cl = lane & 15;
  float sum[4] = {0.f,0.f,0.f,0.f}, ssq[4] = {0.f,0.f,0.f,0.f};
  #pragma unroll
  for (int nt = 0; nt < 16; ++nt) {
    int col = nt * 16 + cl;
    float bs = bias[col];
    #pragma unroll
    for (int r = 0; r < 4; ++r) {
      float v = acc[nt][r] + bs + xf[(size_t)(row0 + r) * D_ + col];
      acc[nt][r] = v;
      xf[(size_t)(row0 + r) * D_ + col] = v;
      sum[r] += v; ssq[r] += v * v;
    }
  }
  #pragma unroll
  for (int r = 0; r < 4; ++r) {
    #pragma unroll
    for (int off = 1; off < 16; off <<= 1) {
      sum[r] += __shfl_xor(sum[r], off, 64);
      ssq[r] += __shfl_xor(ssq[r], off, 64);
    }
  }
  float mu[4], rs[4];
  #pragma unroll
  for (int r = 0; r < 4; ++r) {
    mu[r] = sum[r] * (1.0f / D_);
    float var = ssq[r] * (1.0f / D_) - mu[r] * mu[r];
    rs[r] = rsqrtf(var + 1e-5f);
  }
  #pragma unroll
  for (int nt = 0; nt < 16; ++nt) {
    int col = nt * 16 + cl;
    float wv = lw[col], bv = lb[col];
    #pragma unroll
    for (int r = 0; r < 4; ++r)
      xn[(size_t)(row0 + r) * D_ + col] = __float2bfloat16((acc[nt][r] - mu[r]) * rs[r] * wv + bv);
  }
}

// ---------------- fused QKV MFMA GEMM: Wt = packed [768][256] per layer ----------------
__global__ __launch_bounds__(256) void mgemm_qkv(const bf16* __restrict__ Ab,
    const bf16* __restrict__ Wt, const float* __restrict__ bq,
    const float* __restrict__ bk, const float* __restrict__ bv,
    bf16* __restrict__ qo, bf16* __restrict__ ko, bf16* __restrict__ vo)
{
  __shared__ short As[64][40];
  __shared__ short Bs[64][40];
  int t = threadIdx.x;
  int m0 = blockIdx.y * 64, n0g = blockIdx.x * 64;
  int w = t >> 6, lane = t & 63;
  int srow = t >> 2, sseg = t & 3;
  f32x4 acc[4] = {{0.f,0.f,0.f,0.f},{0.f,0.f,0.f,0.f},{0.f,0.f,0.f,0.f},{0.f,0.f,0.f,0.f}};
  int mf = w * 16 + (lane & 15);
  int kf = (lane >> 4) * 8;
  const bf16* pA = Ab + (size_t)(m0 + srow) * 256 + sseg * 8;
  const bf16* pB = Wt + (size_t)(n0g + srow) * 256 + sseg * 8;
  uint4 ra = *(const uint4*)pA;
  uint4 rb = *(const uint4*)pB;
  for (int k0 = 0; k0 < 256; k0 += 32) {
    *(uint4*)&As[srow][sseg * 8] = ra;
    *(uint4*)&Bs[srow][sseg * 8] = rb;
    __syncthreads();
    if (k0 + 32 < 256) {
      ra = *(const uint4*)(pA + k0 + 32);
      rb = *(const uint4*)(pB + k0 + 32);
    }
    short8 a = *(short8*)&As[mf][kf];
    #pragma unroll
    for (int nt = 0; nt < 4; ++nt) {
      short8 bfr = *(short8*)&Bs[nt * 16 + (lane & 15)][kf];
      acc[nt] = __builtin_amdgcn_mfma_f32_16x16x32_bf16(a, bfr, acc[nt], 0, 0, 0);
    }
    __syncthreads();
  }
  int seg = n0g >> 8;
  const float* bb = (seg == 0 ? bq : (seg == 1 ? bk : bv));
  bf16* dst = (seg == 0 ? qo : (seg == 1 ? ko : vo));
  int row0 = m0 + w * 16 + (lane >> 4) * 4;
  #pragma unroll
  for (int nt = 0; nt < 4; ++nt) {
    int col = (n0g & 255) + nt * 16 + (lane & 15);
    float bs = bb[col];
    #pragma unroll
    for (int r = 0; r < 4; ++r)
      dst[(size_t)(row0 + r) * 256 + col] = __float2bfloat16(acc[nt][r] + bs);
  }
}

// ---------------- MFMA flash attention (round-12, works) ----------------
__global__ __launch_bounds__(256) void k_flash(const bf16* __restrict__ q,
    const bf16* __restrict__ k, const bf16* __restrict__ v, bf16* __restrict__ o)
{
  int qt = blockIdx.x, h = blockIdx.y, b = blockIdx.z;
  int t = threadIdx.x;
  int w = t >> 6, lane = t & 63;
  int quad = lane >> 4, l16 = lane & 15;
  __shared__ short Ks[64][40];
  __shared__ short Vt[32][76];
  __shared__ short Pl[4][16][72];
  short8 a_q = *(const short8*)&q[((size_t)(b * M_) + qt * 64 + w * 16 + l16) * D_ + h * 32 + quad * 8];
  f32x4 o_acc[2] = {{0.f,0.f,0.f,0.f},{0.f,0.f,0.f,0.f}};
  float l_acc[4] = {0.f, 0.f, 0.f, 0.f};
  int skey = t >> 2, sseg = t & 3;
  const float scale = 0.17677669529663687f;
  for (int kt = 0; kt < 16; ++kt) {
    __syncthreads();
    *(short8*)&Ks[skey][sseg * 8] =
        *(const short8*)&k[((size_t)(b * M_) + kt * 64 + skey) * D_ + h * 32 + sseg * 8];
    short8 vv = *(const short8*)&v[((size_t)(b * M_) + kt * 64 + skey) * D_ + h * 32 + sseg * 8];
    #pragma unroll
    for (int i = 0; i < 8; ++i) Vt[sseg * 8 + i][skey] = vv[i];
    __syncthreads();
    #pragma unroll
    for (int st = 0; st < 4; ++st) {
      short8 bf = *(short8*)&Ks[st * 16 + l16][quad * 8];
      f32x4 s4 = __builtin_amdgcn_mfma_f32_16x16x32_bf16(a_q, bf, (f32x4){0.f,0.f,0.f,0.f}, 0, 0, 0);
      #pragma unroll
      for (int r = 0; r < 4; ++r) {
        float p = __expf(s4[r] * scale);
        l_acc[r] += p;
        bf16 hb = __float2bfloat16(p);
        Pl[w][quad * 4 + r][st * 16 + l16] = *reinterpret_cast<short*>(&hb);
      }
    }
    asm volatile("s_waitcnt lgkmcnt(0)" ::: "memory");
    #pragma unroll
    for (int kh = 0; kh < 2; ++kh) {
      short8 a_p = *(short8*)&Pl[w][l16][kh * 32 + quad * 8];
      #pragma unroll
      for (int nt = 0; nt < 2; ++nt) {
        short8 b_v = *(short8*)&Vt[nt * 16 + l16][kh * 32 + quad * 8];
        o_acc[nt] = __builtin_amdgcn_mfma_f32_16x16x32_bf16(a_p, b_v, o_acc[nt], 0, 0, 0);
      }
    }
  }
  #pragma unroll
  for (int r = 0; r < 4; ++r) {
    float lv = l_acc[r];
    lv += __shfl_xor(lv, 1, 64);
    lv += __shfl_xor(lv, 2, 64);
    lv += __shfl_xor(lv, 4, 64);
    lv += __shfl_xor(lv, 8, 64);
    l_acc[r] = 1.0f / lv;
  }
  #pragma unroll
  for (int nt = 0; nt < 2; ++nt)
    #pragma unroll
    for (int r = 0; r < 4; ++r)
      o[((size_t)(b * M_) + qt * 64 + w * 16 + quad * 4 + r) * D_ + h * 32 + nt * 16 + l16] =
          __float2bfloat16(o_acc[nt][r] * l_acc[r]);
}

// ---------------- fused s head: gram->LN->proj for tile pair + symmetrize, direct out ----------------
__global__ __launch_bounds__(256) void k_shead(const bf16* __restrict__ q3,
    const bf16* __restrict__ k3, const float* __restrict__ snw, const float* __restrict__ snb,
    const float* __restrict__ sfw, const float* __restrict__ sfb, float* __restrict__ outs)
{
  int p = blockIdx.x, b = blockIdx.z;
  int it = 0;
  while ((it + 1) * (it + 2) / 2 <= p) ++it;
  int jt = p - it * (it + 1) / 2;
  int t = threadIdx.x;
  int w = t >> 6, lane = t & 63;
  int quad = lane >> 4, l16 = lane & 15;
  __shared__ float Sa[64][65], Sb[64][65];
  const float scale = 0.17677669529663687f;
  float wsn[H_], bsn[H_], wsf[H_];
  #pragma unroll
  for (int h = 0; h < H_; ++h) { wsn[h] = snw[h]; bsn[h] = snb[h]; wsf[h] = sfw[h]; }
  float bias0 = sfb[0];
  #pragma unroll
  for (int tile = 0; tile < 2; ++tile) {
    if (tile == 1 && it == jt) break;
    int rt = (tile == 0 ? it : jt);   // q-row tile
    int ct = (tile == 0 ? jt : it);   // k-col tile
    float (*S)[65] = (tile == 0 ? Sa : Sb);
    short8 aqs[H_];
    #pragma unroll
    for (int h = 0; h < H_; ++h)
      aqs[h] = *(const short8*)&q3[((size_t)(b * M_) + rt * 64 + w * 16 + l16) * D_ + h * 32 + quad * 8];
    #pragma unroll
    for (int cf = 0; cf < 4; ++cf) {
      f32x4 s4[H_];
      #pragma unroll
      for (int h = 0; h < H_; ++h) {
        short8 bk = *(const short8*)&k3[((size_t)(b * M_) + ct * 64 + cf * 16 + l16) * D_ + h * 32 + quad * 8];
        s4[h] = __builtin_amdgcn_mfma_f32_16x16x32_bf16(aqs[h], bk, (f32x4){0.f,0.f,0.f,0.f}, 0, 0, 0);
      }
      #pragma unroll
      for (int r = 0; r < 4; ++r) {
        float d8[H_], ssum = 0.f, ssq = 0.f;
        #pragma unroll
        for (int h = 0; h < H_; ++h) {
          float s = s4[h][r] * scale;
          d8[h] = s; ssum += s; ssq += s * s;
        }
        float mu = ssum * 0.125f;
        float var = ssq * 0.125f - mu * mu;
        float rstd = rsqrtf(var + 1e-5f);
        float val = bias0;
        #pragma unroll
        for (int h = 0; h < H_; ++h)
          val += ((d8[h] - mu) * rstd * wsn[h] + bsn[h]) * wsf[h];
        S[w * 16 + quad * 4 + r][cf * 16 + l16] = val;
      }
    }
  }
  __syncthreads();
  bool diag = (it == jt);
  int i = t >> 2, j0 = (t & 3) * 16;
  #pragma unroll
  for (int jj = 0; jj < 16; ++jj) {
    int j = j0 + jj;
    float sb = diag ? Sa[j][i] : Sb[j][i];
    outs[((size_t)(b * M_) + it * 64 + i) * M_ + jt * 64 + j] = 0.5f * (Sa[i][j] + sb);
  }
  if (!diag) {
    #pragma unroll
    for (int ii = 0; ii < 16; ++ii) {
      int i2 = j0 + ii;   // column index into Sa
      outs[((size_t)(b * M_) + jt * 64 + i) * M_ + it * 64 + i2] = 0.5f * (Sb[i][i2] + Sa[i2][i]);
    }
  }
}

extern "C" void kernel_launch(void* const* d_in, const int* in_sizes, int n_in,
                              void* d_out, int out_size, void* d_ws, size_t ws_size,
                              hipStream_t stream)
{
  const float* X    = (const float*)d_in[0];
  const float* fW   = (const float*)d_in[2];
  const float* fb   = (const float*)d_in[3];
  const float* cW   = (const float*)d_in[4];
  const float* cb   = (const float*)d_in[5];
  const float* Wq   = (const float*)d_in[6];
  const float* bq   = (const float*)d_in[7];
  const float* Wk   = (const float*)d_in[8];
  const float* bk   = (const float*)d_in[9];
  const float* Wv   = (const float*)d_in[10];
  const float* bv   = (const float*)d_in[11];
  const float* Wo   = (const float*)d_in[12];
  const float* bo   = (const float*)d_in[13];
  const float* ln1w = (const float*)d_in[14];
  const float* ln1b = (const float*)d_in[15];
  const float* ln2w = (const float*)d_in[16];
  const float* ln2b = (const float*)d_in[17];
  const float* lnfw = (const float*)d_in[18];
  const float* lnfb = (const float*)d_in[19];
  const float* uw   = (const float*)d_in[20];
  const float* ub   = (const float*)d_in[21];
  const float* dw   = (const float*)d_in[22];
  const float* db   = (const float*)d_in[23];
  const float* finw = (const float*)d_in[24];
  const float* finb = (const float*)d_in[25];
  const float* snw  = (const float*)d_in[26];
  const float* snb  = (const float*)d_in[27];
  const float* sfw  = (const float*)d_in[28];
  const float* sfb  = (const float*)d_in[29];

  char* base = (char*)d_ws;
  const size_t MiB = 1024 * 1024;
  bf16* q_b   = (bf16*)(base + 0 * MiB);              // layer-3 q lives until s head
  bf16* k_b   = (bf16*)(base + 2 * MiB);              // layer-3 k lives until s head
  bf16* wqkvt = (bf16*)(base + 4 * MiB);              // 1.5 MiB: 4 layers x [768][256]
  bf16* wot   = (bf16*)(base + 5 * MiB + 512 * 1024); // 512 KiB
  bf16* uwt   = (bf16*)(base + 6 * MiB);              // 2 MiB
  bf16* dwt   = (bf16*)(base + 8 * MiB);              // 2 MiB
  bf16* fwt   = (bf16*)(base + 10 * MiB);             // 32 KiB
  float* x    = (float*)(base + 10 * MiB + 512 * 1024); // 4 MiB
  char* SR    = base + 14 * MiB + 512 * 1024;
  bf16* xn_b  = (bf16*)(SR + 0 * MiB);
  bf16* v_b   = (bf16*)(SR + 2 * MiB);
  bf16* att_b = (bf16*)(SR + 4 * MiB);
  bf16* h1_b  = (bf16*)(SR + 6 * MiB);
  float* outx = (float*)d_out;
  float* outs = outx + (size_t)BM_TOT * 64;

  dim3 blk(256);
  wconv_all<<<dim3(772), blk, 0, stream>>>(Wq, Wk, Wv, Wo, uw, dw, finw,
                                           wqkvt, wot, uwt, dwt, fwt);
  k_embed_ln<<<dim3(BM_TOT), blk, 0, stream>>>(X, fW, fb, cW, cb, ln1w, ln1b, x, xn_b);
  for (int l = 0; l < L_; ++l) {
    mgemm_qkv<<<dim3(12, 64), blk, 0, stream>>>(xn_b, wqkvt + (size_t)l * 196608,
                                                bq + l * D_, bk + l * D_, bv + l * D_,
                                                q_b, k_b, v_b);
    k_flash<<<dim3(16, H_, B_), blk, 0, stream>>>(q_b, k_b, v_b, att_b);
    // att @ Wo + bo + x -> x ; LN(ln2) -> xn
    mgemm_ln<<<dim3(64), blk, 0, stream>>>(att_b, wot + (size_t)l * 65536, bo + l * D_,
                                           ln2w + l * D_, ln2b + l * D_, x, xn_b, 256);
    mgemm<<<dim3(16, 64), blk, 0, stream>>>(xn_b, uwt + (size_t)l * 262144, ub + l * DFF_,
                                            nullptr, nullptr, h1_b, 256, 1024, 1 | 4);
    // h1 @ dw + db + x -> x ; LN(next ln1 or lnf) -> xn
    const float* nw = (l < 3) ? (ln1w + (l + 1) * D_) : lnfw;
    const float* nb = (l < 3) ? (ln1b + (l + 1) * D_) : lnfb;
    mgemm_ln<<<dim3(64), blk, 0, stream>>>(h1_b, dwt + (size_t)l * 262144, db + l * D_,
                                           nw, nb, x, xn_b, 1024);
  }
  mgemm<<<dim3(1, 64), blk, 0, stream>>>(xn_b, fwt, finb, nullptr, outx, nullptr, 256, 64, 8);
  // layer-3 q/k still live in q_b/k_b
  k_shead<<<dim3(136, 1, B_), blk, 0, stream>>>(q_b, k_b, snw, snb, sfw, sfb, outs);
}

// Round 2
// 540.976 us; speedup vs baseline: 1.2109x; 1.2109x over previous
//
#include <hip/hip_runtime.h>
#include <hip/hip_bf16.h>
#include <math.h>

#define B_ 4
#define M_ 1024
#define NIN 70
#define D_ 256
#define H_ 8
#define L_ 4
#define DFF_ 1024
#define BM_TOT 4096

typedef __hip_bfloat16 bf16;
typedef short short8 __attribute__((ext_vector_type(8)));
typedef float f32x4 __attribute__((ext_vector_type(4)));

// ---------------- single-launch weight convert+transpose ----------------
// All weights -> bf16 [N][K] (row stride = K). QKV packed per layer as [768][256].
__global__ __launch_bounds__(256) void wconv_all(
    const float* __restrict__ Wq, const float* __restrict__ Wk, const float* __restrict__ Wv,
    const float* __restrict__ Wo, const float* __restrict__ uw, const float* __restrict__ dw,
    const float* __restrict__ finw,
    bf16* __restrict__ wqkvt, bf16* __restrict__ wot, bf16* __restrict__ uwt,
    bf16* __restrict__ dwt, bf16* __restrict__ fwt)
{
  __shared__ float T[64][65];
  int idx = blockIdx.x;
  const float* src; bf16* dst; int K, N, k0, n0, rbase, S;
  if (idx < 192) {            // Wq/Wk/Wv -> wqkvt[l][m*256 + n][k]
    int m = idx >> 6; int r = idx & 63; int l = r >> 4; int tt = r & 15;
    int kt = tt >> 2, nt = tt & 3;
    src = (m == 0 ? Wq : (m == 1 ? Wk : Wv)) + (size_t)l * 65536;
    K = 256; N = 256; k0 = kt * 64; n0 = nt * 64;
    dst = wqkvt + (size_t)l * 196608; rbase = m * 256 + nt * 64; S = 256;
  } else if (idx < 256) {     // Wo
    int r = idx - 192; int l = r >> 4; int tt = r & 15; int kt = tt >> 2, nt = tt & 3;
    src = Wo + (size_t)l * 65536; K = 256; N = 256; k0 = kt * 64; n0 = nt * 64;
    dst = wot + (size_t)l * 65536; rbase = nt * 64; S = 256;
  } else if (idx < 512) {     // uw (256 x 1024)
    int r = idx - 256; int l = r >> 6; int tt = r & 63; int kt = tt >> 4, nt = tt & 15;
    src = uw + (size_t)l * 262144; K = 256; N = 1024; k0 = kt * 64; n0 = nt * 64;
    dst = uwt + (size_t)l * 262144; rbase = nt * 64; S = 256;
  } else if (idx < 768) {     // dw (1024 x 256)
    int r = idx - 512; int l = r >> 6; int tt = r & 63; int kt = tt >> 2, nt = tt & 3;
    src = dw + (size_t)l * 262144; K = 1024; N = 256; k0 = kt * 64; n0 = nt * 64;
    dst = dwt + (size_t)l * 262144; rbase = nt * 64; S = 1024;
  } else {                    // finw (256 x 64)
    int kt = idx - 768;
    src = finw; K = 256; N = 64; k0 = kt * 64; n0 = 0;
    dst = fwt; rbase = 0; S = 256;
  }
  int t = threadIdx.x;
  int kl = t >> 2, ns = (t & 3) * 16;
  #pragma unroll
  for (int i = 0; i < 16; i += 4)
    *(float4*)&T[kl][ns + i] = *(const float4*)&src[(size_t)(k0 + kl) * N + n0 + ns + i];
  __syncthreads();
  int nl = t >> 2, ks = (t & 3) * 16;
  __align__(16) bf16 tmp[16];
  #pragma unroll
  for (int i = 0; i < 16; ++i) tmp[i] = __float2bfloat16(T[ks + i][nl]);
  *(uint4*)&dst[(size_t)(rbase + nl) * S + k0 + ks] = *(uint4*)&tmp[0];
  *(uint4*)&dst[(size_t)(rbase + nl) * S + k0 + ks + 8] = *(uint4*)&tmp[8];
}

// ---------------- embedding fused with layer-0 ln1 ----------------
__global__ __launch_bounds__(256) void k_embed_ln(const float* __restrict__ X,
    const float* __restrict__ fW, const float* __restrict__ fb,
    const float* __restrict__ cW, const float* __restrict__ cb,
    const float* __restrict__ lw, const float* __restrict__ lb,
    float* __restrict__ x, bf16* __restrict__ xn)
{
  int bm = blockIdx.x;
  int d = threadIdx.x;
  __shared__ float xr[NIN];
  __shared__ float red[8];
  if (d < NIN) xr[d] = X[bm * NIN + d];
  __syncthreads();
  int f = d & 127;
  float proj = xr[0] * fW[f * 3 + 0] + xr[1] * fW[f * 3 + 1]
             + xr[2] * fW[f * 3 + 2] + fb[f];
  float pe = (d < 128 ? cosf(proj) : sinf(proj)) * 0.17677669529663687f;
  float acc = pe + cb[d];
  #pragma unroll 8
  for (int c = 0; c < 64; ++c)
    acc += xr[6 + c] * cW[c * D_ + d];
  x[bm * D_ + d] = acc;
  // LN over the 256 values (4 waves)
  float s = acc, q = acc * acc;
  #pragma unroll
  for (int off = 32; off; off >>= 1) {
    s += __shfl_xor(s, off, 64);
    q += __shfl_xor(q, off, 64);
  }
  int wave = d >> 6, lane = d & 63;
  if (lane == 0) { red[wave * 2] = s; red[wave * 2 + 1] = q; }
  __syncthreads();
  float ts = red[0] + red[2] + red[4] + red[6];
  float tq = red[1] + red[3] + red[5] + red[7];
  float mu = ts * (1.0f / D_);
  float var = tq * (1.0f / D_) - mu * mu;
  float rstd = rsqrtf(var + 1e-5f);
  xn[bm * D_ + d] = __float2bfloat16((acc - mu) * rstd * lw[d] + lb[d]);
}

// ---------------- layernorm: fp32 in -> bf16 out ----------------
__global__ __launch_bounds__(256) void k_ln(const float* __restrict__ xin,
    const float* __restrict__ w, const float* __restrict__ b, bf16* __restrict__ xout)
{
  int wave = threadIdx.x >> 6;
  int lane = threadIdx.x & 63;
  int row = blockIdx.x * 4 + wave;
  float4 xv = *(const float4*)&xin[row * D_ + lane * 4];
  float s = xv.x + xv.y + xv.z + xv.w;
  float q = xv.x * xv.x + xv.y * xv.y + xv.z * xv.z + xv.w * xv.w;
  #pragma unroll
  for (int off = 32; off; off >>= 1) {
    s += __shfl_xor(s, off, 64);
    q += __shfl_xor(q, off, 64);
  }
  float mu = s * (1.0f / D_);
  float var = q * (1.0f / D_) - mu * mu;
  float rstd = rsqrtf(var + 1e-5f);
  float4 wv = *(const float4*)&w[lane * 4];
  float4 bv = *(const float4*)&b[lane * 4];
  __align__(8) bf16 tmp[4];
  tmp[0] = __float2bfloat16((xv.x - mu) * rstd * wv.x + bv.x);
  tmp[1] = __float2bfloat16((xv.y - mu) * rstd * wv.y + bv.y);
  tmp[2] = __float2bfloat16((xv.z - mu) * rstd * wv.z + bv.z);
  tmp[3] = __float2bfloat16((xv.w - mu) * rstd * wv.w + bv.w);
  *(uint2*)&xout[row * D_ + lane * 4] = *(uint2*)tmp;
}

// ---------------- single-wave no-LDS 32x32 MFMA GEMM ----------------
// One wave per block, 32x32 output tile, fragments loaded directly from
// global (L2-resident operands), no barriers -> compiler pipelines via vmcnt.
// Grid: (M/32, N/32) with M on x so col-blocks sharing an A strip land on
// the same XCD (id stride 128 = 0 mod 8).
__global__ __launch_bounds__(64) void sgemm32(const bf16* __restrict__ Ab,
    const bf16* __restrict__ Wt, const float* __restrict__ bias,
    const float* __restrict__ Res, float* __restrict__ Cf, bf16* __restrict__ Cb,
    int K, int N, int flags)
{
  int lane = threadIdx.x;
  int l16 = lane & 15, quad = lane >> 4;
  int m0 = blockIdx.x * 32, n0 = blockIdx.y * 32;
  const bf16* pa0 = Ab + (size_t)(m0 + l16) * K + quad * 8;
  const bf16* pa1 = pa0 + (size_t)16 * K;
  const bf16* pb0 = Wt + (size_t)(n0 + l16) * K + quad * 8;
  const bf16* pb1 = pb0 + (size_t)16 * K;
  f32x4 acc00 = {0.f,0.f,0.f,0.f}, acc01 = {0.f,0.f,0.f,0.f};
  f32x4 acc10 = {0.f,0.f,0.f,0.f}, acc11 = {0.f,0.f,0.f,0.f};
  short8 a0 = *(const short8*)pa0;
  short8 a1 = *(const short8*)pa1;
  short8 b0 = *(const short8*)pb0;
  short8 b1 = *(const short8*)pb1;
  #pragma unroll 2
  for (int k0 = 0; k0 < K; k0 += 32) {
    short8 na0, na1, nb0, nb1;
    bool more = (k0 + 32) < K;
    if (more) {
      na0 = *(const short8*)(pa0 + k0 + 32);
      na1 = *(const short8*)(pa1 + k0 + 32);
      nb0 = *(const short8*)(pb0 + k0 + 32);
      nb1 = *(const short8*)(pb1 + k0 + 32);
    }
    acc00 = __builtin_amdgcn_mfma_f32_16x16x32_bf16(a0, b0, acc00, 0, 0, 0);
    acc01 = __builtin_amdgcn_mfma_f32_16x16x32_bf16(a0, b1, acc01, 0, 0, 0);
    acc10 = __builtin_amdgcn_mfma_f32_16x16x32_bf16(a1, b0, acc10, 0, 0, 0);
    acc11 = __builtin_amdgcn_mfma_f32_16x16x32_bf16(a1, b1, acc11, 0, 0, 0);
    if (more) { a0 = na0; a1 = na1; b0 = nb0; b1 = nb1; }
  }
  f32x4 accv[2][2] = {{acc00, acc01}, {acc10, acc11}};
  #pragma unroll
  for (int rg = 0; rg < 2; ++rg) {
    int row0 = m0 + rg * 16 + quad * 4;
    #pragma unroll
    for (int cg = 0; cg < 2; ++cg) {
      int col = n0 + cg * 16 + l16;
      float bs = bias[col];
      #pragma unroll
      for (int r = 0; r < 4; ++r) {
        float v = accv[rg][cg][r] + bs;
        if (flags & 1) v = 0.5f * v * (1.0f + erff(v * 0.70710678118654752f));
        if (flags & 2) v += Res[(size_t)(row0 + r) * N + col];
        if (flags & 8) Cf[(size_t)(row0 + r) * N + col] = v;
        if (flags & 4) Cb[(size_t)(row0 + r) * N + col] = __float2bfloat16(v);
      }
    }
  }
}

// ---------------- fused QKV MFMA GEMM: Wt = packed [768][256] per layer ----------------
__global__ __launch_bounds__(256) void mgemm_qkv(const bf16* __restrict__ Ab,
    const bf16* __restrict__ Wt, const float* __restrict__ bq,
    const float* __restrict__ bk, const float* __restrict__ bv,
    bf16* __restrict__ qo, bf16* __restrict__ ko, bf16* __restrict__ vo)
{
  __shared__ short As[64][40];
  __shared__ short Bs[64][40];
  int t = threadIdx.x;
  int m0 = blockIdx.y * 64, n0g = blockIdx.x * 64;
  int w = t >> 6, lane = t & 63;
  int srow = t >> 2, sseg = t & 3;
  f32x4 acc[4] = {{0.f,0.f,0.f,0.f},{0.f,0.f,0.f,0.f},{0.f,0.f,0.f,0.f},{0.f,0.f,0.f,0.f}};
  int mf = w * 16 + (lane & 15);
  int kf = (lane >> 4) * 8;
  for (int k0 = 0; k0 < 256; k0 += 32) {
    *(uint4*)&As[srow][sseg * 8] = *(const uint4*)&Ab[(size_t)(m0 + srow) * 256 + k0 + sseg * 8];
    *(uint4*)&Bs[srow][sseg * 8] = *(const uint4*)&Wt[(size_t)(n0g + srow) * 256 + k0 + sseg * 8];
    __syncthreads();
    short8 a = *(short8*)&As[mf][kf];
    #pragma unroll
    for (int nt = 0; nt < 4; ++nt) {
      short8 bfr = *(short8*)&Bs[nt * 16 + (lane & 15)][kf];
      acc[nt] = __builtin_amdgcn_mfma_f32_16x16x32_bf16(a, bfr, acc[nt], 0, 0, 0);
    }
    __syncthreads();
  }
  int seg = n0g >> 8;
  const float* bb = (seg == 0 ? bq : (seg == 1 ? bk : bv));
  bf16* dst = (seg == 0 ? qo : (seg == 1 ? ko : vo));
  int row0 = m0 + w * 16 + (lane >> 4) * 4;
  #pragma unroll
  for (int nt = 0; nt < 4; ++nt) {
    int col = (n0g & 255) + nt * 16 + (lane & 15);
    float bs = bb[col];
    #pragma unroll
    for (int r = 0; r < 4; ++r)
      dst[(size_t)(row0 + r) * 256 + col] = __float2bfloat16(acc[nt][r] + bs);
  }
}

// ---------------- MFMA flash attention (round-12, works) ----------------
__global__ __launch_bounds__(256) void k_flash(const bf16* __restrict__ q,
    const bf16* __restrict__ k, const bf16* __restrict__ v, bf16* __restrict__ o)
{
  int qt = blockIdx.x, h = blockIdx.y, b = blockIdx.z;
  int t = threadIdx.x;
  int w = t >> 6, lane = t & 63;
  int quad = lane >> 4, l16 = lane & 15;
  __shared__ short Ks[64][40];
  __shared__ short Vt[32][76];
  __shared__ short Pl[4][16][72];
  short8 a_q = *(const short8*)&q[((size_t)(b * M_) + qt * 64 + w * 16 + l16) * D_ + h * 32 + quad * 8];
  f32x4 o_acc[2] = {{0.f,0.f,0.f,0.f},{0.f,0.f,0.f,0.f}};
  float l_acc[4] = {0.f, 0.f, 0.f, 0.f};
  int skey = t >> 2, sseg = t & 3;
  const float scale = 0.17677669529663687f;
  for (int kt = 0; kt < 16; ++kt) {
    __syncthreads();
    *(short8*)&Ks[skey][sseg * 8] =
        *(const short8*)&k[((size_t)(b * M_) + kt * 64 + skey) * D_ + h * 32 + sseg * 8];
    short8 vv = *(const short8*)&v[((size_t)(b * M_) + kt * 64 + skey) * D_ + h * 32 + sseg * 8];
    #pragma unroll
    for (int i = 0; i < 8; ++i) Vt[sseg * 8 + i][skey] = vv[i];
    __syncthreads();
    #pragma unroll
    for (int st = 0; st < 4; ++st) {
      short8 bf = *(short8*)&Ks[st * 16 + l16][quad * 8];
      f32x4 s4 = __builtin_amdgcn_mfma_f32_16x16x32_bf16(a_q, bf, (f32x4){0.f,0.f,0.f,0.f}, 0, 0, 0);
      #pragma unroll
      for (int r = 0; r < 4; ++r) {
        float p = __expf(s4[r] * scale);
        l_acc[r] += p;
        bf16 hb = __float2bfloat16(p);
        Pl[w][quad * 4 + r][st * 16 + l16] = *reinterpret_cast<short*>(&hb);
      }
    }
    asm volatile("s_waitcnt lgkmcnt(0)" ::: "memory");
    #pragma unroll
    for (int kh = 0; kh < 2; ++kh) {
      short8 a_p = *(short8*)&Pl[w][l16][kh * 32 + quad * 8];
      #pragma unroll
      for (int nt = 0; nt < 2; ++nt) {
        short8 b_v = *(short8*)&Vt[nt * 16 + l16][kh * 32 + quad * 8];
        o_acc[nt] = __builtin_amdgcn_mfma_f32_16x16x32_bf16(a_p, b_v, o_acc[nt], 0, 0, 0);
      }
    }
  }
  #pragma unroll
  for (int r = 0; r < 4; ++r) {
    float lv = l_acc[r];
    lv += __shfl_xor(lv, 1, 64);
    lv += __shfl_xor(lv, 2, 64);
    lv += __shfl_xor(lv, 4, 64);
    lv += __shfl_xor(lv, 8, 64);
    l_acc[r] = 1.0f / lv;
  }
  #pragma unroll
  for (int nt = 0; nt < 2; ++nt)
    #pragma unroll
    for (int r = 0; r < 4; ++r)
      o[((size_t)(b * M_) + qt * 64 + w * 16 + quad * 4 + r) * D_ + h * 32 + nt * 16 + l16] =
          __float2bfloat16(o_acc[nt][r] * l_acc[r]);
}

// ---------------- fused s head: gram->LN->proj for tile pair + symmetrize, direct out ----------------
__global__ __launch_bounds__(256) void k_shead(const bf16* __restrict__ q3,
    const bf16* __restrict__ k3, const float* __restrict__ snw, const float* __restrict__ snb,
    const float* __restrict__ sfw, const float* __restrict__ sfb, float* __restrict__ outs)
{
  int p = blockIdx.x, b = blockIdx.z;
  int it = 0;
  while ((it + 1) * (it + 2) / 2 <= p) ++it;
  int jt = p - it * (it + 1) / 2;
  int t = threadIdx.x;
  int w = t >> 6, lane = t & 63;
  int quad = lane >> 4, l16 = lane & 15;
  __shared__ float Sa[64][65], Sb[64][65];
  const float scale = 0.17677669529663687f;
  float wsn[H_], bsn[H_], wsf[H_];
  #pragma unroll
  for (int h = 0; h < H_; ++h) { wsn[h] = snw[h]; bsn[h] = snb[h]; wsf[h] = sfw[h]; }
  float bias0 = sfb[0];
  #pragma unroll
  for (int tile = 0; tile < 2; ++tile) {
    if (tile == 1 && it == jt) break;
    int rt = (tile == 0 ? it : jt);   // q-row tile
    int ct = (tile == 0 ? jt : it);   // k-col tile
    float (*S)[65] = (tile == 0 ? Sa : Sb);
    short8 aqs[H_];
    #pragma unroll
    for (int h = 0; h < H_; ++h)
      aqs[h] = *(const short8*)&q3[((size_t)(b * M_) + rt * 64 + w * 16 + l16) * D_ + h * 32 + quad * 8];
    #pragma unroll
    for (int cf = 0; cf < 4; ++cf) {
      f32x4 s4[H_];
      #pragma unroll
      for (int h = 0; h < H_; ++h) {
        short8 bk = *(const short8*)&k3[((size_t)(b * M_) + ct * 64 + cf * 16 + l16) * D_ + h * 32 + quad * 8];
        s4[h] = __builtin_amdgcn_mfma_f32_16x16x32_bf16(aqs[h], bk, (f32x4){0.f,0.f,0.f,0.f}, 0, 0, 0);
      }
      #pragma unroll
      for (int r = 0; r < 4; ++r) {
        float d8[H_], ssum = 0.f, ssq = 0.f;
        #pragma unroll
        for (int h = 0; h < H_; ++h) {
          float s = s4[h][r] * scale;
          d8[h] = s; ssum += s; ssq += s * s;
        }
        float mu = ssum * 0.125f;
        float var = ssq * 0.125f - mu * mu;
        float rstd = rsqrtf(var + 1e-5f);
        float val = bias0;
        #pragma unroll
        for (int h = 0; h < H_; ++h)
          val += ((d8[h] - mu) * rstd * wsn[h] + bsn[h]) * wsf[h];
        S[w * 16 + quad * 4 + r][cf * 16 + l16] = val;
      }
    }
  }
  __syncthreads();
  bool diag = (it == jt);
  int i = t >> 2, j0 = (t & 3) * 16;
  #pragma unroll
  for (int jj = 0; jj < 16; ++jj) {
    int j = j0 + jj;
    float sb = diag ? Sa[j][i] : Sb[j][i];
    outs[((size_t)(b * M_) + it * 64 + i) * M_ + jt * 64 + j] = 0.5f * (Sa[i][j] + sb);
  }
  if (!diag) {
    #pragma unroll
    for (int ii = 0; ii < 16; ++ii) {
      int i2 = j0 + ii;   // column index into Sa
      outs[((size_t)(b * M_) + jt * 64 + i) * M_ + it * 64 + i2] = 0.5f * (Sb[i][i2] + Sa[i2][i]);
    }
  }
}

extern "C" void kernel_launch(void* const* d_in, const int* in_sizes, int n_in,
                              void* d_out, int out_size, void* d_ws, size_t ws_size,
                              hipStream_t stream)
{
  const float* X    = (const float*)d_in[0];
  const float* fW   = (const float*)d_in[2];
  const float* fb   = (const float*)d_in[3];
  const float* cW   = (const float*)d_in[4];
  const float* cb   = (const float*)d_in[5];
  const float* Wq   = (const float*)d_in[6];
  const float* bq   = (const float*)d_in[7];
  const float* Wk   = (const float*)d_in[8];
  const float* bk   = (const float*)d_in[9];
  const float* Wv   = (const float*)d_in[10];
  const float* bv   = (const float*)d_in[11];
  const float* Wo   = (const float*)d_in[12];
  const float* bo   = (const float*)d_in[13];
  const float* ln1w = (const float*)d_in[14];
  const float* ln1b = (const float*)d_in[15];
  const float* ln2w = (const float*)d_in[16];
  const float* ln2b = (const float*)d_in[17];
  const float* lnfw = (const float*)d_in[18];
  const float* lnfb = (const float*)d_in[19];
  const float* uw   = (const float*)d_in[20];
  const float* ub   = (const float*)d_in[21];
  const float* dw   = (const float*)d_in[22];
  const float* db   = (const float*)d_in[23];
  const float* finw = (const float*)d_in[24];
  const float* finb = (const float*)d_in[25];
  const float* snw  = (const float*)d_in[26];
  const float* snb  = (const float*)d_in[27];
  const float* sfw  = (const float*)d_in[28];
  const float* sfb  = (const float*)d_in[29];

  char* base = (char*)d_ws;
  const size_t MiB = 1024 * 1024;
  bf16* q_b   = (bf16*)(base + 0 * MiB);              // layer-3 q lives until s head
  bf16* k_b   = (bf16*)(base + 2 * MiB);              // layer-3 k lives until s head
  bf16* wqkvt = (bf16*)(base + 4 * MiB);              // 1.5 MiB: 4 layers x [768][256]
  bf16* wot   = (bf16*)(base + 5 * MiB + 512 * 1024); // 512 KiB
  bf16* uwt   = (bf16*)(base + 6 * MiB);              // 2 MiB
  bf16* dwt   = (bf16*)(base + 8 * MiB);              // 2 MiB
  bf16* fwt   = (bf16*)(base + 10 * MiB);             // 32 KiB
  float* x    = (float*)(base + 10 * MiB + 512 * 1024); // 4 MiB
  char* SR    = base + 14 * MiB + 512 * 1024;
  bf16* xn_b  = (bf16*)(SR + 0 * MiB);
  bf16* v_b   = (bf16*)(SR + 2 * MiB);
  bf16* att_b = (bf16*)(SR + 4 * MiB);
  bf16* h1_b  = (bf16*)(SR + 6 * MiB);
  float* outx = (float*)d_out;
  float* outs = outx + (size_t)BM_TOT * 64;

  dim3 blk(256);
  dim3 sblk(64);
  wconv_all<<<dim3(772), blk, 0, stream>>>(Wq, Wk, Wv, Wo, uw, dw, finw,
                                           wqkvt, wot, uwt, dwt, fwt);
  k_embed_ln<<<dim3(BM_TOT), blk, 0, stream>>>(X, fW, fb, cW, cb, ln1w, ln1b, x, xn_b);
  for (int l = 0; l < L_; ++l) {
    if (l > 0)
      k_ln<<<dim3(BM_TOT / 4), blk, 0, stream>>>(x, ln1w + l * D_, ln1b + l * D_, xn_b);
    mgemm_qkv<<<dim3(12, 64), blk, 0, stream>>>(xn_b, wqkvt + (size_t)l * 196608,
                                                bq + l * D_, bk + l * D_, bv + l * D_,
                                                q_b, k_b, v_b);
    k_flash<<<dim3(16, H_, B_), blk, 0, stream>>>(q_b, k_b, v_b, att_b);
    // att @ Wo + bo + x -> x (fp32)
    sgemm32<<<dim3(128, 8), sblk, 0, stream>>>(att_b, wot + (size_t)l * 65536, bo + l * D_,
                                               x, x, nullptr, 256, 256, 2 | 8);
    k_ln<<<dim3(BM_TOT / 4), blk, 0, stream>>>(x, ln2w + l * D_, ln2b + l * D_, xn_b);
    // xn @ uw + ub, gelu -> h1 (bf16)
    sgemm32<<<dim3(128, 32), sblk, 0, stream>>>(xn_b, uwt + (size_t)l * 262144, ub + l * DFF_,
                                                nullptr, nullptr, h1_b, 256, 1024, 1 | 4);
    // h1 @ dw + db + x -> x (fp32)
    sgemm32<<<dim3(128, 8), sblk, 0, stream>>>(h1_b, dwt + (size_t)l * 262144, db + l * D_,
                                               x, x, nullptr, 1024, 256, 2 | 8);
  }
  k_ln<<<dim3(BM_TOT / 4), blk, 0, stream>>>(x, lnfw, lnfb, xn_b);
  sgemm32<<<dim3(128, 2), sblk, 0, stream>>>(xn_b, fwt, finb, nullptr, outx, nullptr, 256, 64, 8);
  // layer-3 q/k still live in q_b/k_b
  k_shead<<<dim3(136, 1, B_), blk, 0, stream>>>(q_b, k_b, snw, snb, sfw, sfb, outs);
}

// Round 3
// 536.853 us; speedup vs baseline: 1.2202x; 1.0077x over previous
//
#include <hip/hip_runtime.h>
#include <hip/hip_bf16.h>
#include <math.h>

#define B_ 4
#define M_ 1024
#define NIN 70
#define D_ 256
#define H_ 8
#define L_ 4
#define DFF_ 1024
#define BM_TOT 4096

typedef __hip_bfloat16 bf16;
typedef short short8 __attribute__((ext_vector_type(8)));
typedef float f32x4 __attribute__((ext_vector_type(4)));

// ---------------- single-launch weight convert+transpose ----------------
// All weights -> bf16 [N][K] (row stride = K). QKV packed per layer as [768][256].
__global__ __launch_bounds__(256) void wconv_all(
    const float* __restrict__ Wq, const float* __restrict__ Wk, const float* __restrict__ Wv,
    const float* __restrict__ Wo, const float* __restrict__ uw, const float* __restrict__ dw,
    const float* __restrict__ finw,
    bf16* __restrict__ wqkvt, bf16* __restrict__ wot, bf16* __restrict__ uwt,
    bf16* __restrict__ dwt, bf16* __restrict__ fwt)
{
  __shared__ float T[64][65];
  int idx = blockIdx.x;
  const float* src; bf16* dst; int K, N, k0, n0, rbase, S;
  if (idx < 192) {            // Wq/Wk/Wv -> wqkvt[l][m*256 + n][k]
    int m = idx >> 6; int r = idx & 63; int l = r >> 4; int tt = r & 15;
    int kt = tt >> 2, nt = tt & 3;
    src = (m == 0 ? Wq : (m == 1 ? Wk : Wv)) + (size_t)l * 65536;
    K = 256; N = 256; k0 = kt * 64; n0 = nt * 64;
    dst = wqkvt + (size_t)l * 196608; rbase = m * 256 + nt * 64; S = 256;
  } else if (idx < 256) {     // Wo
    int r = idx - 192; int l = r >> 4; int tt = r & 15; int kt = tt >> 2, nt = tt & 3;
    src = Wo + (size_t)l * 65536; K = 256; N = 256; k0 = kt * 64; n0 = nt * 64;
    dst = wot + (size_t)l * 65536; rbase = nt * 64; S = 256;
  } else if (idx < 512) {     // uw (256 x 1024)
    int r = idx - 256; int l = r >> 6; int tt = r & 63; int kt = tt >> 4, nt = tt & 15;
    src = uw + (size_t)l * 262144; K = 256; N = 1024; k0 = kt * 64; n0 = nt * 64;
    dst = uwt + (size_t)l * 262144; rbase = nt * 64; S = 256;
  } else if (idx < 768) {     // dw (1024 x 256)
    int r = idx - 512; int l = r >> 6; int tt = r & 63; int kt = tt >> 2, nt = tt & 3;
    src = dw + (size_t)l * 262144; K = 1024; N = 256; k0 = kt * 64; n0 = nt * 64;
    dst = dwt + (size_t)l * 262144; rbase = nt * 64; S = 1024;
  } else {                    // finw (256 x 64)
    int kt = idx - 768;
    src = finw; K = 256; N = 64; k0 = kt * 64; n0 = 0;
    dst = fwt; rbase = 0; S = 256;
  }
  int t = threadIdx.x;
  int kl = t >> 2, ns = (t & 3) * 16;
  #pragma unroll
  for (int i = 0; i < 16; i += 4)
    *(float4*)&T[kl][ns + i] = *(const float4*)&src[(size_t)(k0 + kl) * N + n0 + ns + i];
  __syncthreads();
  int nl = t >> 2, ks = (t & 3) * 16;
  __align__(16) bf16 tmp[16];
  #pragma unroll
  for (int i = 0; i < 16; ++i) tmp[i] = __float2bfloat16(T[ks + i][nl]);
  *(uint4*)&dst[(size_t)(rbase + nl) * S + k0 + ks] = *(uint4*)&tmp[0];
  *(uint4*)&dst[(size_t)(rbase + nl) * S + k0 + ks + 8] = *(uint4*)&tmp[8];
}

// ---------------- embedding: 4 rows/block, no LN (ln1 fused into qkv GEMM) ----------------
__global__ __launch_bounds__(256) void k_embed(const float* __restrict__ X,
    const float* __restrict__ fW, const float* __restrict__ fb,
    const float* __restrict__ cW, const float* __restrict__ cb,
    float* __restrict__ x)
{
  int bm0 = blockIdx.x * 4;
  int d = threadIdx.x;
  __shared__ float xr[4][NIN];
  for (int i = d; i < 4 * NIN; i += 256)
    xr[i / NIN][i % NIN] = X[(size_t)(bm0 + i / NIN) * NIN + i % NIN];
  __syncthreads();
  int f = d & 127;
  float fw0 = fW[f * 3 + 0], fw1 = fW[f * 3 + 1], fw2 = fW[f * 3 + 2], fbv = fb[f];
  float cbv = cb[d];
  float acc[4];
  #pragma unroll
  for (int r = 0; r < 4; ++r) {
    float proj = xr[r][0] * fw0 + xr[r][1] * fw1 + xr[r][2] * fw2 + fbv;
    acc[r] = (d < 128 ? cosf(proj) : sinf(proj)) * 0.17677669529663687f + cbv;
  }
  #pragma unroll 8
  for (int c = 0; c < 64; ++c) {
    float cw = cW[c * D_ + d];
    #pragma unroll
    for (int r = 0; r < 4; ++r) acc[r] += xr[r][6 + c] * cw;
  }
  #pragma unroll
  for (int r = 0; r < 4; ++r)
    x[(size_t)(bm0 + r) * D_ + d] = acc[r];
}

// ---------------- MFMA GEMM (reg-prefetch pipelined; used for wo and dw) ----------------
__global__ __launch_bounds__(256) void mgemm(const bf16* __restrict__ Ab,
    const bf16* __restrict__ Wt, const float* __restrict__ bias,
    const float* __restrict__ Res, float* __restrict__ Cf, bf16* __restrict__ Cb,
    int K, int N, int flags)
{
  __shared__ short As[64][40];
  __shared__ short Bs[64][40];
  int t = threadIdx.x;
  int m0 = blockIdx.y * 64, n0 = blockIdx.x * 64;
  int w = t >> 6, lane = t & 63;
  int srow = t >> 2, sseg = t & 3;
  f32x4 acc[4] = {{0.f,0.f,0.f,0.f},{0.f,0.f,0.f,0.f},{0.f,0.f,0.f,0.f},{0.f,0.f,0.f,0.f}};
  int mf = w * 16 + (lane & 15);
  int kf = (lane >> 4) * 8;
  const bf16* pA = Ab + (size_t)(m0 + srow) * K + sseg * 8;
  const bf16* pB = Wt + (size_t)(n0 + srow) * K + sseg * 8;
  uint4 ra = *(const uint4*)pA;
  uint4 rb = *(const uint4*)pB;
  for (int k0 = 0; k0 < K; k0 += 32) {
    *(uint4*)&As[srow][sseg * 8] = ra;
    *(uint4*)&Bs[srow][sseg * 8] = rb;
    __syncthreads();
    if (k0 + 32 < K) {
      ra = *(const uint4*)(pA + k0 + 32);
      rb = *(const uint4*)(pB + k0 + 32);
    }
    short8 a = *(short8*)&As[mf][kf];
    #pragma unroll
    for (int nt = 0; nt < 4; ++nt) {
      short8 bfr = *(short8*)&Bs[nt * 16 + (lane & 15)][kf];
      acc[nt] = __builtin_amdgcn_mfma_f32_16x16x32_bf16(a, bfr, acc[nt], 0, 0, 0);
    }
    __syncthreads();
  }
  int row0 = m0 + w * 16 + (lane >> 4) * 4;
  #pragma unroll
  for (int nt = 0; nt < 4; ++nt) {
    int col = n0 + nt * 16 + (lane & 15);
    float bs = bias[col];
    #pragma unroll
    for (int r = 0; r < 4; ++r) {
      float v = acc[nt][r] + bs;
      if (flags & 1) v = 0.5f * v * (1.0f + erff(v * 0.70710678118654752f));
      if (flags & 2) v += Res[(size_t)(row0 + r) * N + col];
      if (flags & 8) Cf[(size_t)(row0 + r) * N + col] = v;
      if (flags & 4) Cb[(size_t)(row0 + r) * N + col] = __float2bfloat16(v);
    }
  }
}

// ---------------- MFMA GEMM with LN-fused A prologue (K=256) ----------------
// A = LayerNorm(xf) computed in-block: each thread owns (row, quarter), loads 64
// fp32, row-reduces over 4 lanes, packs bf16 into full-width LDS A [64][264].
// K-loop stages only B (reg-prefetched). Used for uw and final projection.
__global__ __launch_bounds__(256) void mgemm_lnA(const float* __restrict__ xf,
    const bf16* __restrict__ Wt, const float* __restrict__ bias,
    const float* __restrict__ lw, const float* __restrict__ lb,
    float* __restrict__ Cf, bf16* __restrict__ Cb, int N, int flags)
{
  __shared__ short As[64][264];
  __shared__ short Bs[64][40];
  __shared__ float lws[256], lbs[256];
  int t = threadIdx.x;
  int m0 = blockIdx.y * 64, n0 = blockIdx.x * 64;
  int row = t >> 2, q = t & 3;
  lws[t] = lw[t]; lbs[t] = lb[t];
  const bf16* pB = Wt + (size_t)(n0 + row) * 256 + q * 8;
  uint4 rb = *(const uint4*)pB;
  const float* pX = xf + (size_t)(m0 + row) * 256 + q * 64;
  float4 ar[16];
  #pragma unroll
  for (int i = 0; i < 16; ++i) ar[i] = *(const float4*)(pX + i * 4);
  float s = 0.f, ss = 0.f;
  #pragma unroll
  for (int i = 0; i < 16; ++i) {
    s  += ar[i].x + ar[i].y + ar[i].z + ar[i].w;
    ss += ar[i].x * ar[i].x + ar[i].y * ar[i].y + ar[i].z * ar[i].z + ar[i].w * ar[i].w;
  }
  s  += __shfl_xor(s, 1, 64);  ss += __shfl_xor(ss, 1, 64);
  s  += __shfl_xor(s, 2, 64);  ss += __shfl_xor(ss, 2, 64);
  float mu = s * (1.0f / D_);
  float rstd = rsqrtf(ss * (1.0f / D_) - mu * mu + 1e-5f);
  __syncthreads();            // lws/lbs visible
  #pragma unroll
  for (int i = 0; i < 16; ++i) {
    int c = q * 64 + i * 4;
    __align__(8) bf16 tb[4];
    tb[0] = __float2bfloat16((ar[i].x - mu) * rstd * lws[c + 0] + lbs[c + 0]);
    tb[1] = __float2bfloat16((ar[i].y - mu) * rstd * lws[c + 1] + lbs[c + 1]);
    tb[2] = __float2bfloat16((ar[i].z - mu) * rstd * lws[c + 2] + lbs[c + 2]);
    tb[3] = __float2bfloat16((ar[i].w - mu) * rstd * lws[c + 3] + lbs[c + 3]);
    *(uint2*)&As[row][c] = *(uint2*)tb;
  }
  int w = t >> 6, lane = t & 63;
  int mf = w * 16 + (lane & 15);
  int kf = (lane >> 4) * 8;
  f32x4 acc[4] = {{0.f,0.f,0.f,0.f},{0.f,0.f,0.f,0.f},{0.f,0.f,0.f,0.f},{0.f,0.f,0.f,0.f}};
  for (int k0 = 0; k0 < 256; k0 += 32) {
    *(uint4*)&Bs[row][q * 8] = rb;
    __syncthreads();          // first iter also covers As writes
    if (k0 + 32 < 256) rb = *(const uint4*)(pB + k0 + 32);
    short8 a = *(short8*)&As[mf][k0 + kf];
    #pragma unroll
    for (int nt = 0; nt < 4; ++nt) {
      short8 bfr = *(short8*)&Bs[nt * 16 + (lane & 15)][kf];
      acc[nt] = __builtin_amdgcn_mfma_f32_16x16x32_bf16(a, bfr, acc[nt], 0, 0, 0);
    }
    __syncthreads();
  }
  int row0 = m0 + w * 16 + (lane >> 4) * 4;
  #pragma unroll
  for (int nt = 0; nt < 4; ++nt) {
    int col = n0 + nt * 16 + (lane & 15);
    float bs = bias[col];
    #pragma unroll
    for (int r = 0; r < 4; ++r) {
      float v = acc[nt][r] + bs;
      if (flags & 1) v = 0.5f * v * (1.0f + erff(v * 0.70710678118654752f));
      if (flags & 8) Cf[(size_t)(row0 + r) * N + col] = v;
      if (flags & 4) Cb[(size_t)(row0 + r) * N + col] = __float2bfloat16(v);
    }
  }
}

// ---------------- QKV GEMM with LN-fused A prologue; Wt packed [768][256] ----------------
__global__ __launch_bounds__(256) void mgemm_qkv_lnA(const float* __restrict__ xf,
    const bf16* __restrict__ Wt,
    const float* __restrict__ lw, const float* __restrict__ lb,
    const float* __restrict__ bq, const float* __restrict__ bk, const float* __restrict__ bv,
    bf16* __restrict__ qo, bf16* __restrict__ ko, bf16* __restrict__ vo)
{
  __shared__ short As[64][264];
  __shared__ short Bs[64][40];
  __shared__ float lws[256], lbs[256];
  int t = threadIdx.x;
  int m0 = blockIdx.y * 64, n0g = blockIdx.x * 64;
  int row = t >> 2, q = t & 3;
  lws[t] = lw[t]; lbs[t] = lb[t];
  const bf16* pB = Wt + (size_t)(n0g + row) * 256 + q * 8;
  uint4 rb = *(const uint4*)pB;
  const float* pX = xf + (size_t)(m0 + row) * 256 + q * 64;
  float4 ar[16];
  #pragma unroll
  for (int i = 0; i < 16; ++i) ar[i] = *(const float4*)(pX + i * 4);
  float s = 0.f, ss = 0.f;
  #pragma unroll
  for (int i = 0; i < 16; ++i) {
    s  += ar[i].x + ar[i].y + ar[i].z + ar[i].w;
    ss += ar[i].x * ar[i].x + ar[i].y * ar[i].y + ar[i].z * ar[i].z + ar[i].w * ar[i].w;
  }
  s  += __shfl_xor(s, 1, 64);  ss += __shfl_xor(ss, 1, 64);
  s  += __shfl_xor(s, 2, 64);  ss += __shfl_xor(ss, 2, 64);
  float mu = s * (1.0f / D_);
  float rstd = rsqrtf(ss * (1.0f / D_) - mu * mu + 1e-5f);
  __syncthreads();
  #pragma unroll
  for (int i = 0; i < 16; ++i) {
    int c = q * 64 + i * 4;
    __align__(8) bf16 tb[4];
    tb[0] = __float2bfloat16((ar[i].x - mu) * rstd * lws[c + 0] + lbs[c + 0]);
    tb[1] = __float2bfloat16((ar[i].y - mu) * rstd * lws[c + 1] + lbs[c + 1]);
    tb[2] = __float2bfloat16((ar[i].z - mu) * rstd * lws[c + 2] + lbs[c + 2]);
    tb[3] = __float2bfloat16((ar[i].w - mu) * rstd * lws[c + 3] + lbs[c + 3]);
    *(uint2*)&As[row][c] = *(uint2*)tb;
  }
  int w = t >> 6, lane = t & 63;
  int mf = w * 16 + (lane & 15);
  int kf = (lane >> 4) * 8;
  f32x4 acc[4] = {{0.f,0.f,0.f,0.f},{0.f,0.f,0.f,0.f},{0.f,0.f,0.f,0.f},{0.f,0.f,0.f,0.f}};
  for (int k0 = 0; k0 < 256; k0 += 32) {
    *(uint4*)&Bs[row][q * 8] = rb;
    __syncthreads();
    if (k0 + 32 < 256) rb = *(const uint4*)(pB + k0 + 32);
    short8 a = *(short8*)&As[mf][k0 + kf];
    #pragma unroll
    for (int nt = 0; nt < 4; ++nt) {
      short8 bfr = *(short8*)&Bs[nt * 16 + (lane & 15)][kf];
      acc[nt] = __builtin_amdgcn_mfma_f32_16x16x32_bf16(a, bfr, acc[nt], 0, 0, 0);
    }
    __syncthreads();
  }
  int seg = n0g >> 8;
  const float* bb = (seg == 0 ? bq : (seg == 1 ? bk : bv));
  bf16* dst = (seg == 0 ? qo : (seg == 1 ? ko : vo));
  int row0 = m0 + w * 16 + (lane >> 4) * 4;
  #pragma unroll
  for (int nt = 0; nt < 4; ++nt) {
    int col = (n0g & 255) + nt * 16 + (lane & 15);
    float bs = bb[col];
    #pragma unroll
    for (int r = 0; r < 4; ++r)
      dst[(size_t)(row0 + r) * 256 + col] = __float2bfloat16(acc[nt][r] + bs);
  }
}

// ---------------- MFMA flash attention (round-12, works) ----------------
__global__ __launch_bounds__(256) void k_flash(const bf16* __restrict__ q,
    const bf16* __restrict__ k, const bf16* __restrict__ v, bf16* __restrict__ o)
{
  int qt = blockIdx.x, h = blockIdx.y, b = blockIdx.z;
  int t = threadIdx.x;
  int w = t >> 6, lane = t & 63;
  int quad = lane >> 4, l16 = lane & 15;
  __shared__ short Ks[64][40];
  __shared__ short Vt[32][76];
  __shared__ short Pl[4][16][72];
  short8 a_q = *(const short8*)&q[((size_t)(b * M_) + qt * 64 + w * 16 + l16) * D_ + h * 32 + quad * 8];
  f32x4 o_acc[2] = {{0.f,0.f,0.f,0.f},{0.f,0.f,0.f,0.f}};
  float l_acc[4] = {0.f, 0.f, 0.f, 0.f};
  int skey = t >> 2, sseg = t & 3;
  const float scale = 0.17677669529663687f;
  for (int kt = 0; kt < 16; ++kt) {
    __syncthreads();
    *(short8*)&Ks[skey][sseg * 8] =
        *(const short8*)&k[((size_t)(b * M_) + kt * 64 + skey) * D_ + h * 32 + sseg * 8];
    short8 vv = *(const short8*)&v[((size_t)(b * M_) + kt * 64 + skey) * D_ + h * 32 + sseg * 8];
    #pragma unroll
    for (int i = 0; i < 8; ++i) Vt[sseg * 8 + i][skey] = vv[i];
    __syncthreads();
    #pragma unroll
    for (int st = 0; st < 4; ++st) {
      short8 bf = *(short8*)&Ks[st * 16 + l16][quad * 8];
      f32x4 s4 = __builtin_amdgcn_mfma_f32_16x16x32_bf16(a_q, bf, (f32x4){0.f,0.f,0.f,0.f}, 0, 0, 0);
      #pragma unroll
      for (int r = 0; r < 4; ++r) {
        float p = __expf(s4[r] * scale);
        l_acc[r] += p;
        bf16 hb = __float2bfloat16(p);
        Pl[w][quad * 4 + r][st * 16 + l16] = *reinterpret_cast<short*>(&hb);
      }
    }
    asm volatile("s_waitcnt lgkmcnt(0)" ::: "memory");
    #pragma unroll
    for (int kh = 0; kh < 2; ++kh) {
      short8 a_p = *(short8*)&Pl[w][l16][kh * 32 + quad * 8];
      #pragma unroll
      for (int nt = 0; nt < 2; ++nt) {
        short8 b_v = *(short8*)&Vt[nt * 16 + l16][kh * 32 + quad * 8];
        o_acc[nt] = __builtin_amdgcn_mfma_f32_16x16x32_bf16(a_p, b_v, o_acc[nt], 0, 0, 0);
      }
    }
  }
  #pragma unroll
  for (int r = 0; r < 4; ++r) {
    float lv = l_acc[r];
    lv += __shfl_xor(lv, 1, 64);
    lv += __shfl_xor(lv, 2, 64);
    lv += __shfl_xor(lv, 4, 64);
    lv += __shfl_xor(lv, 8, 64);
    l_acc[r] = 1.0f / lv;
  }
  #pragma unroll
  for (int nt = 0; nt < 2; ++nt)
    #pragma unroll
    for (int r = 0; r < 4; ++r)
      o[((size_t)(b * M_) + qt * 64 + w * 16 + quad * 4 + r) * D_ + h * 32 + nt * 16 + l16] =
          __float2bfloat16(o_acc[nt][r] * l_acc[r]);
}

// ---------------- fused s head: gram->LN->proj for tile pair + symmetrize, direct out ----------------
__global__ __launch_bounds__(256) void k_shead(const bf16* __restrict__ q3,
    const bf16* __restrict__ k3, const float* __restrict__ snw, const float* __restrict__ snb,
    const float* __restrict__ sfw, const float* __restrict__ sfb, float* __restrict__ outs)
{
  int p = blockIdx.x, b = blockIdx.z;
  int it = 0;
  while ((it + 1) * (it + 2) / 2 <= p) ++it;
  int jt = p - it * (it + 1) / 2;
  int t = threadIdx.x;
  int w = t >> 6, lane = t & 63;
  int quad = lane >> 4, l16 = lane & 15;
  __shared__ float Sa[64][65], Sb[64][65];
  const float scale = 0.17677669529663687f;
  float wsn[H_], bsn[H_], wsf[H_];
  #pragma unroll
  for (int h = 0; h < H_; ++h) { wsn[h] = snw[h]; bsn[h] = snb[h]; wsf[h] = sfw[h]; }
  float bias0 = sfb[0];
  #pragma unroll
  for (int tile = 0; tile < 2; ++tile) {
    if (tile == 1 && it == jt) break;
    int rt = (tile == 0 ? it : jt);   // q-row tile
    int ct = (tile == 0 ? jt : it);   // k-col tile
    float (*S)[65] = (tile == 0 ? Sa : Sb);
    short8 aqs[H_];
    #pragma unroll
    for (int h = 0; h < H_; ++h)
      aqs[h] = *(const short8*)&q3[((size_t)(b * M_) + rt * 64 + w * 16 + l16) * D_ + h * 32 + quad * 8];
    #pragma unroll
    for (int cf = 0; cf < 4; ++cf) {
      f32x4 s4[H_];
      #pragma unroll
      for (int h = 0; h < H_; ++h) {
        short8 bk = *(const short8*)&k3[((size_t)(b * M_) + ct * 64 + cf * 16 + l16) * D_ + h * 32 + quad * 8];
        s4[h] = __builtin_amdgcn_mfma_f32_16x16x32_bf16(aqs[h], bk, (f32x4){0.f,0.f,0.f,0.f}, 0, 0, 0);
      }
      #pragma unroll
      for (int r = 0; r < 4; ++r) {
        float d8[H_], ssum = 0.f, ssq = 0.f;
        #pragma unroll
        for (int h = 0; h < H_; ++h) {
          float s = s4[h][r] * scale;
          d8[h] = s; ssum += s; ssq += s * s;
        }
        float mu = ssum * 0.125f;
        float var = ssq * 0.125f - mu * mu;
        float rstd = rsqrtf(var + 1e-5f);
        float val = bias0;
        #pragma unroll
        for (int h = 0; h < H_; ++h)
          val += ((d8[h] - mu) * rstd * wsn[h] + bsn[h]) * wsf[h];
        S[w * 16 + quad * 4 + r][cf * 16 + l16] = val;
      }
    }
  }
  __syncthreads();
  bool diag = (it == jt);
  int i = t >> 2, j0 = (t & 3) * 16;
  #pragma unroll
  for (int jj = 0; jj < 16; ++jj) {
    int j = j0 + jj;
    float sb = diag ? Sa[j][i] : Sb[j][i];
    outs[((size_t)(b * M_) + it * 64 + i) * M_ + jt * 64 + j] = 0.5f * (Sa[i][j] + sb);
  }
  if (!diag) {
    #pragma unroll
    for (int ii = 0; ii < 16; ++ii) {
      int i2 = j0 + ii;   // column index into Sa
      outs[((size_t)(b * M_) + jt * 64 + i) * M_ + it * 64 + i2] = 0.5f * (Sb[i][i2] + Sa[i2][i]);
    }
  }
}

extern "C" void kernel_launch(void* const* d_in, const int* in_sizes, int n_in,
                              void* d_out, int out_size, void* d_ws, size_t ws_size,
                              hipStream_t stream)
{
  const float* X    = (const float*)d_in[0];
  const float* fW   = (const float*)d_in[2];
  const float* fb   = (const float*)d_in[3];
  const float* cW   = (const float*)d_in[4];
  const float* cb   = (const float*)d_in[5];
  const float* Wq   = (const float*)d_in[6];
  const float* bq   = (const float*)d_in[7];
  const float* Wk   = (const float*)d_in[8];
  const float* bk   = (const float*)d_in[9];
  const float* Wv   = (const float*)d_in[10];
  const float* bv   = (const float*)d_in[11];
  const float* Wo   = (const float*)d_in[12];
  const float* bo   = (const float*)d_in[13];
  const float* ln1w = (const float*)d_in[14];
  const float* ln1b = (const float*)d_in[15];
  const float* ln2w = (const float*)d_in[16];
  const float* ln2b = (const float*)d_in[17];
  const float* lnfw = (const float*)d_in[18];
  const float* lnfb = (const float*)d_in[19];
  const float* uw   = (const float*)d_in[20];
  const float* ub   = (const float*)d_in[21];
  const float* dw   = (const float*)d_in[22];
  const float* db   = (const float*)d_in[23];
  const float* finw = (const float*)d_in[24];
  const float* finb = (const float*)d_in[25];
  const float* snw  = (const float*)d_in[26];
  const float* snb  = (const float*)d_in[27];
  const float* sfw  = (const float*)d_in[28];
  const float* sfb  = (const float*)d_in[29];

  char* base = (char*)d_ws;
  const size_t MiB = 1024 * 1024;
  bf16* q_b   = (bf16*)(base + 0 * MiB);              // layer-3 q lives until s head
  bf16* k_b   = (bf16*)(base + 2 * MiB);              // layer-3 k lives until s head
  bf16* wqkvt = (bf16*)(base + 4 * MiB);              // 1.5 MiB: 4 layers x [768][256]
  bf16* wot   = (bf16*)(base + 5 * MiB + 512 * 1024); // 512 KiB
  bf16* uwt   = (bf16*)(base + 6 * MiB);              // 2 MiB
  bf16* dwt   = (bf16*)(base + 8 * MiB);              // 2 MiB
  bf16* fwt   = (bf16*)(base + 10 * MiB);             // 32 KiB
  float* x    = (float*)(base + 10 * MiB + 512 * 1024); // 4 MiB
  char* SR    = base + 14 * MiB + 512 * 1024;
  bf16* v_b   = (bf16*)(SR + 2 * MiB);
  bf16* att_b = (bf16*)(SR + 4 * MiB);
  bf16* h1_b  = (bf16*)(SR + 6 * MiB);
  float* outx = (float*)d_out;
  float* outs = outx + (size_t)BM_TOT * 64;

  dim3 blk(256);
  wconv_all<<<dim3(772), blk, 0, stream>>>(Wq, Wk, Wv, Wo, uw, dw, finw,
                                           wqkvt, wot, uwt, dwt, fwt);
  k_embed<<<dim3(BM_TOT / 4), blk, 0, stream>>>(X, fW, fb, cW, cb, x);
  for (int l = 0; l < L_; ++l) {
    // qkv = (ln1(x)) @ Wqkv + b  (LN fused in prologue)
    mgemm_qkv_lnA<<<dim3(12, 64), blk, 0, stream>>>(x, wqkvt + (size_t)l * 196608,
                                                    ln1w + l * D_, ln1b + l * D_,
                                                    bq + l * D_, bk + l * D_, bv + l * D_,
                                                    q_b, k_b, v_b);
    k_flash<<<dim3(16, H_, B_), blk, 0, stream>>>(q_b, k_b, v_b, att_b);
    // x += att @ Wo + bo
    mgemm<<<dim3(4, 64), blk, 0, stream>>>(att_b, wot + (size_t)l * 65536, bo + l * D_,
                                           x, x, nullptr, 256, 256, 2 | 8);
    // h1 = gelu(ln2(x) @ uw + ub)  (LN fused)
    mgemm_lnA<<<dim3(16, 64), blk, 0, stream>>>(x, uwt + (size_t)l * 262144, ub + l * DFF_,
                                                ln2w + l * D_, ln2b + l * D_,
                                                nullptr, h1_b, 1024, 1 | 4);
    // x += h1 @ dw + db
    mgemm<<<dim3(4, 64), blk, 0, stream>>>(h1_b, dwt + (size_t)l * 262144, db + l * D_,
                                           x, x, nullptr, 1024, 256, 2 | 8);
  }
  // outx = lnf(x) @ finw + finb  (LN fused)
  mgemm_lnA<<<dim3(1, 64), blk, 0, stream>>>(x, fwt, finb, lnfw, lnfb,
                                             outx, nullptr, 64, 8);
  // layer-3 q/k still live in q_b/k_b
  k_shead<<<dim3(136, 1, B_), blk, 0, stream>>>(q_b, k_b, snw, snb, sfw, sfb, outs);
}

// Round 4
// 490.707 us; speedup vs baseline: 1.3350x; 1.0940x over previous
//
#include <hip/hip_runtime.h>
#include <hip/hip_bf16.h>
#include <math.h>

#define B_ 4
#define M_ 1024
#define NIN 70
#define D_ 256
#define H_ 8
#define L_ 4
#define DFF_ 1024
#define BM_TOT 4096

typedef __hip_bfloat16 bf16;
typedef short short8 __attribute__((ext_vector_type(8)));
typedef float f32x4 __attribute__((ext_vector_type(4)));

// ---------------- single-launch weight convert+transpose ----------------
// All weights -> bf16 [N][K] (row stride = K). QKV packed per layer as [768][256].
__global__ __launch_bounds__(256) void wconv_all(
    const float* __restrict__ Wq, const float* __restrict__ Wk, const float* __restrict__ Wv,
    const float* __restrict__ Wo, const float* __restrict__ uw, const float* __restrict__ dw,
    const float* __restrict__ finw,
    bf16* __restrict__ wqkvt, bf16* __restrict__ wot, bf16* __restrict__ uwt,
    bf16* __restrict__ dwt, bf16* __restrict__ fwt)
{
  __shared__ float T[64][65];
  int idx = blockIdx.x;
  const float* src; bf16* dst; int K, N, k0, n0, rbase, S;
  if (idx < 192) {            // Wq/Wk/Wv -> wqkvt[l][m*256 + n][k]
    int m = idx >> 6; int r = idx & 63; int l = r >> 4; int tt = r & 15;
    int kt = tt >> 2, nt = tt & 3;
    src = (m == 0 ? Wq : (m == 1 ? Wk : Wv)) + (size_t)l * 65536;
    K = 256; N = 256; k0 = kt * 64; n0 = nt * 64;
    dst = wqkvt + (size_t)l * 196608; rbase = m * 256 + nt * 64; S = 256;
  } else if (idx < 256) {     // Wo
    int r = idx - 192; int l = r >> 4; int tt = r & 15; int kt = tt >> 2, nt = tt & 3;
    src = Wo + (size_t)l * 65536; K = 256; N = 256; k0 = kt * 64; n0 = nt * 64;
    dst = wot + (size_t)l * 65536; rbase = nt * 64; S = 256;
  } else if (idx < 512) {     // uw (256 x 1024)
    int r = idx - 256; int l = r >> 6; int tt = r & 63; int kt = tt >> 4, nt = tt & 15;
    src = uw + (size_t)l * 262144; K = 256; N = 1024; k0 = kt * 64; n0 = nt * 64;
    dst = uwt + (size_t)l * 262144; rbase = nt * 64; S = 256;
  } else if (idx < 768) {     // dw (1024 x 256)
    int r = idx - 512; int l = r >> 6; int tt = r & 63; int kt = tt >> 2, nt = tt & 3;
    src = dw + (size_t)l * 262144; K = 1024; N = 256; k0 = kt * 64; n0 = nt * 64;
    dst = dwt + (size_t)l * 262144; rbase = nt * 64; S = 1024;
  } else {                    // finw (256 x 64)
    int kt = idx - 768;
    src = finw; K = 256; N = 64; k0 = kt * 64; n0 = 0;
    dst = fwt; rbase = 0; S = 256;
  }
  int t = threadIdx.x;
  int kl = t >> 2, ns = (t & 3) * 16;
  #pragma unroll
  for (int i = 0; i < 16; i += 4)
    *(float4*)&T[kl][ns + i] = *(const float4*)&src[(size_t)(k0 + kl) * N + n0 + ns + i];
  __syncthreads();
  int nl = t >> 2, ks = (t & 3) * 16;
  __align__(16) bf16 tmp[16];
  #pragma unroll
  for (int i = 0; i < 16; ++i) tmp[i] = __float2bfloat16(T[ks + i][nl]);
  *(uint4*)&dst[(size_t)(rbase + nl) * S + k0 + ks] = *(uint4*)&tmp[0];
  *(uint4*)&dst[(size_t)(rbase + nl) * S + k0 + ks + 8] = *(uint4*)&tmp[8];
}

// ---------------- embedding: 4 rows/block ----------------
__global__ __launch_bounds__(256) void k_embed(const float* __restrict__ X,
    const float* __restrict__ fW, const float* __restrict__ fb,
    const float* __restrict__ cW, const float* __restrict__ cb,
    float* __restrict__ x)
{
  int bm0 = blockIdx.x * 4;
  int d = threadIdx.x;
  __shared__ float xr[4][NIN];
  for (int i = d; i < 4 * NIN; i += 256)
    xr[i / NIN][i % NIN] = X[(size_t)(bm0 + i / NIN) * NIN + i % NIN];
  __syncthreads();
  int f = d & 127;
  float fw0 = fW[f * 3 + 0], fw1 = fW[f * 3 + 1], fw2 = fW[f * 3 + 2], fbv = fb[f];
  float cbv = cb[d];
  float acc[4];
  #pragma unroll
  for (int r = 0; r < 4; ++r) {
    float proj = xr[r][0] * fw0 + xr[r][1] * fw1 + xr[r][2] * fw2 + fbv;
    acc[r] = (d < 128 ? cosf(proj) : sinf(proj)) * 0.17677669529663687f + cbv;
  }
  #pragma unroll 8
  for (int c = 0; c < 64; ++c) {
    float cw = cW[c * D_ + d];
    #pragma unroll
    for (int r = 0; r < 4; ++r) acc[r] += xr[r][6 + c] * cw;
  }
  #pragma unroll
  for (int r = 0; r < 4; ++r)
    x[(size_t)(bm0 + r) * D_ + d] = acc[r];
}

// ---------------- layernorm: fp32 in -> bf16 out ----------------
__global__ __launch_bounds__(256) void k_ln(const float* __restrict__ xin,
    const float* __restrict__ w, const float* __restrict__ b, bf16* __restrict__ xout)
{
  int wave = threadIdx.x >> 6;
  int lane = threadIdx.x & 63;
  int row = blockIdx.x * 4 + wave;
  float4 xv = *(const float4*)&xin[row * D_ + lane * 4];
  float s = xv.x + xv.y + xv.z + xv.w;
  float q = xv.x * xv.x + xv.y * xv.y + xv.z * xv.z + xv.w * xv.w;
  #pragma unroll
  for (int off = 32; off; off >>= 1) {
    s += __shfl_xor(s, off, 64);
    q += __shfl_xor(q, off, 64);
  }
  float mu = s * (1.0f / D_);
  float var = q * (1.0f / D_) - mu * mu;
  float rstd = rsqrtf(var + 1e-5f);
  float4 wv = *(const float4*)&w[lane * 4];
  float4 bv = *(const float4*)&b[lane * 4];
  __align__(8) bf16 tmp[4];
  tmp[0] = __float2bfloat16((xv.x - mu) * rstd * wv.x + bv.x);
  tmp[1] = __float2bfloat16((xv.y - mu) * rstd * wv.y + bv.y);
  tmp[2] = __float2bfloat16((xv.z - mu) * rstd * wv.z + bv.z);
  tmp[3] = __float2bfloat16((xv.w - mu) * rstd * wv.w + bv.w);
  *(uint2*)&xout[row * D_ + lane * 4] = *(uint2*)tmp;
}

// ---------------- MFMA GEMM (reg-prefetch pipelined, R1-proven) ----------------
__global__ __launch_bounds__(256) void mgemm(const bf16* __restrict__ Ab,
    const bf16* __restrict__ Wt, const float* __restrict__ bias,
    const float* __restrict__ Res, float* __restrict__ Cf, bf16* __restrict__ Cb,
    int K, int N, int flags)
{
  __shared__ short As[64][40];
  __shared__ short Bs[64][40];
  int t = threadIdx.x;
  int m0 = blockIdx.y * 64, n0 = blockIdx.x * 64;
  int w = t >> 6, lane = t & 63;
  int srow = t >> 2, sseg = t & 3;
  f32x4 acc[4] = {{0.f,0.f,0.f,0.f},{0.f,0.f,0.f,0.f},{0.f,0.f,0.f,0.f},{0.f,0.f,0.f,0.f}};
  int mf = w * 16 + (lane & 15);
  int kf = (lane >> 4) * 8;
  const bf16* pA = Ab + (size_t)(m0 + srow) * K + sseg * 8;
  const bf16* pB = Wt + (size_t)(n0 + srow) * K + sseg * 8;
  uint4 ra = *(const uint4*)pA;
  uint4 rb = *(const uint4*)pB;
  for (int k0 = 0; k0 < K; k0 += 32) {
    *(uint4*)&As[srow][sseg * 8] = ra;
    *(uint4*)&Bs[srow][sseg * 8] = rb;
    __syncthreads();
    if (k0 + 32 < K) {
      ra = *(const uint4*)(pA + k0 + 32);
      rb = *(const uint4*)(pB + k0 + 32);
    }
    short8 a = *(short8*)&As[mf][kf];
    #pragma unroll
    for (int nt = 0; nt < 4; ++nt) {
      short8 bfr = *(short8*)&Bs[nt * 16 + (lane & 15)][kf];
      acc[nt] = __builtin_amdgcn_mfma_f32_16x16x32_bf16(a, bfr, acc[nt], 0, 0, 0);
    }
    __syncthreads();
  }
  int row0 = m0 + w * 16 + (lane >> 4) * 4;
  #pragma unroll
  for (int nt = 0; nt < 4; ++nt) {
    int col = n0 + nt * 16 + (lane & 15);
    float bs = bias[col];
    #pragma unroll
    for (int r = 0; r < 4; ++r) {
      float v = acc[nt][r] + bs;
      if (flags & 1) v = 0.5f * v * (1.0f + erff(v * 0.70710678118654752f));
      if (flags & 2) v += Res[(size_t)(row0 + r) * N + col];
      if (flags & 8) Cf[(size_t)(row0 + r) * N + col] = v;
      if (flags & 4) Cb[(size_t)(row0 + r) * N + col] = __float2bfloat16(v);
    }
  }
}

// ---------------- fused QKV MFMA GEMM (reg-prefetch, R1-proven) ----------------
__global__ __launch_bounds__(256) void mgemm_qkv(const bf16* __restrict__ Ab,
    const bf16* __restrict__ Wt, const float* __restrict__ bq,
    const float* __restrict__ bk, const float* __restrict__ bv,
    bf16* __restrict__ qo, bf16* __restrict__ ko, bf16* __restrict__ vo)
{
  __shared__ short As[64][40];
  __shared__ short Bs[64][40];
  int t = threadIdx.x;
  int m0 = blockIdx.y * 64, n0g = blockIdx.x * 64;
  int w = t >> 6, lane = t & 63;
  int srow = t >> 2, sseg = t & 3;
  f32x4 acc[4] = {{0.f,0.f,0.f,0.f},{0.f,0.f,0.f,0.f},{0.f,0.f,0.f,0.f},{0.f,0.f,0.f,0.f}};
  int mf = w * 16 + (lane & 15);
  int kf = (lane >> 4) * 8;
  const bf16* pA = Ab + (size_t)(m0 + srow) * 256 + sseg * 8;
  const bf16* pB = Wt + (size_t)(n0g + srow) * 256 + sseg * 8;
  uint4 ra = *(const uint4*)pA;
  uint4 rb = *(const uint4*)pB;
  for (int k0 = 0; k0 < 256; k0 += 32) {
    *(uint4*)&As[srow][sseg * 8] = ra;
    *(uint4*)&Bs[srow][sseg * 8] = rb;
    __syncthreads();
    if (k0 + 32 < 256) {
      ra = *(const uint4*)(pA + k0 + 32);
      rb = *(const uint4*)(pB + k0 + 32);
    }
    short8 a = *(short8*)&As[mf][kf];
    #pragma unroll
    for (int nt = 0; nt < 4; ++nt) {
      short8 bfr = *(short8*)&Bs[nt * 16 + (lane & 15)][kf];
      acc[nt] = __builtin_amdgcn_mfma_f32_16x16x32_bf16(a, bfr, acc[nt], 0, 0, 0);
    }
    __syncthreads();
  }
  int seg = n0g >> 8;
  const float* bb = (seg == 0 ? bq : (seg == 1 ? bk : bv));
  bf16* dst = (seg == 0 ? qo : (seg == 1 ? ko : vo));
  int row0 = m0 + w * 16 + (lane >> 4) * 4;
  #pragma unroll
  for (int nt = 0; nt < 4; ++nt) {
    int col = (n0g & 255) + nt * 16 + (lane & 15);
    float bs = bb[col];
    #pragma unroll
    for (int r = 0; r < 4; ++r)
      dst[(size_t)(row0 + r) * 256 + col] = __float2bfloat16(acc[nt][r] + bs);
  }
}

// ---------------- MFMA flash attention (unchanged) ----------------
__global__ __launch_bounds__(256) void k_flash(const bf16* __restrict__ q,
    const bf16* __restrict__ k, const bf16* __restrict__ v, bf16* __restrict__ o)
{
  int qt = blockIdx.x, h = blockIdx.y, b = blockIdx.z;
  int t = threadIdx.x;
  int w = t >> 6, lane = t & 63;
  int quad = lane >> 4, l16 = lane & 15;
  __shared__ short Ks[64][40];
  __shared__ short Vt[32][76];
  __shared__ short Pl[4][16][72];
  short8 a_q = *(const short8*)&q[((size_t)(b * M_) + qt * 64 + w * 16 + l16) * D_ + h * 32 + quad * 8];
  f32x4 o_acc[2] = {{0.f,0.f,0.f,0.f},{0.f,0.f,0.f,0.f}};
  float l_acc[4] = {0.f, 0.f, 0.f, 0.f};
  int skey = t >> 2, sseg = t & 3;
  const float scale = 0.17677669529663687f;
  for (int kt = 0; kt < 16; ++kt) {
    __syncthreads();
    *(short8*)&Ks[skey][sseg * 8] =
        *(const short8*)&k[((size_t)(b * M_) + kt * 64 + skey) * D_ + h * 32 + sseg * 8];
    short8 vv = *(const short8*)&v[((size_t)(b * M_) + kt * 64 + skey) * D_ + h * 32 + sseg * 8];
    #pragma unroll
    for (int i = 0; i < 8; ++i) Vt[sseg * 8 + i][skey] = vv[i];
    __syncthreads();
    #pragma unroll
    for (int st = 0; st < 4; ++st) {
      short8 bf = *(short8*)&Ks[st * 16 + l16][quad * 8];
      f32x4 s4 = __builtin_amdgcn_mfma_f32_16x16x32_bf16(a_q, bf, (f32x4){0.f,0.f,0.f,0.f}, 0, 0, 0);
      #pragma unroll
      for (int r = 0; r < 4; ++r) {
        float p = __expf(s4[r] * scale);
        l_acc[r] += p;
        bf16 hb = __float2bfloat16(p);
        Pl[w][quad * 4 + r][st * 16 + l16] = *reinterpret_cast<short*>(&hb);
      }
    }
    asm volatile("s_waitcnt lgkmcnt(0)" ::: "memory");
    #pragma unroll
    for (int kh = 0; kh < 2; ++kh) {
      short8 a_p = *(short8*)&Pl[w][l16][kh * 32 + quad * 8];
      #pragma unroll
      for (int nt = 0; nt < 2; ++nt) {
        short8 b_v = *(short8*)&Vt[nt * 16 + l16][kh * 32 + quad * 8];
        o_acc[nt] = __builtin_amdgcn_mfma_f32_16x16x32_bf16(a_p, b_v, o_acc[nt], 0, 0, 0);
      }
    }
  }
  #pragma unroll
  for (int r = 0; r < 4; ++r) {
    float lv = l_acc[r];
    lv += __shfl_xor(lv, 1, 64);
    lv += __shfl_xor(lv, 2, 64);
    lv += __shfl_xor(lv, 4, 64);
    lv += __shfl_xor(lv, 8, 64);
    l_acc[r] = 1.0f / lv;
  }
  #pragma unroll
  for (int nt = 0; nt < 2; ++nt)
    #pragma unroll
    for (int r = 0; r < 4; ++r)
      o[((size_t)(b * M_) + qt * 64 + w * 16 + quad * 4 + r) * D_ + h * 32 + nt * 16 + l16] =
          __float2bfloat16(o_acc[nt][r] * l_acc[r]);
}

// ---------------- s head stage 1: one 64x64 tile per block, no LDS/barriers ----------------
// Computes raw (pre-symmetrize) s values: gram over heads -> head-LN -> proj,
// written coalesced to stmp[b][row][col].
__global__ __launch_bounds__(256) void k_shead1(const bf16* __restrict__ q3,
    const bf16* __restrict__ k3, const float* __restrict__ snw, const float* __restrict__ snb,
    const float* __restrict__ sfw, const float* __restrict__ sfb, float* __restrict__ stmp)
{
  int ct = blockIdx.x, rt = blockIdx.y, b = blockIdx.z;
  int t = threadIdx.x;
  int w = t >> 6, lane = t & 63;
  int quad = lane >> 4, l16 = lane & 15;
  const float scale = 0.17677669529663687f;
  float wsn[H_], bsn[H_], wsf[H_];
  #pragma unroll
  for (int h = 0; h < H_; ++h) { wsn[h] = snw[h]; bsn[h] = snb[h]; wsf[h] = sfw[h]; }
  float bias0 = sfb[0];
  short8 aqs[H_];
  #pragma unroll
  for (int h = 0; h < H_; ++h)
    aqs[h] = *(const short8*)&q3[((size_t)(b * M_) + rt * 64 + w * 16 + l16) * D_ + h * 32 + quad * 8];
  #pragma unroll
  for (int cf = 0; cf < 4; ++cf) {
    f32x4 s4[H_];
    #pragma unroll
    for (int h = 0; h < H_; ++h) {
      short8 bk = *(const short8*)&k3[((size_t)(b * M_) + ct * 64 + cf * 16 + l16) * D_ + h * 32 + quad * 8];
      s4[h] = __builtin_amdgcn_mfma_f32_16x16x32_bf16(aqs[h], bk, (f32x4){0.f,0.f,0.f,0.f}, 0, 0, 0);
    }
    #pragma unroll
    for (int r = 0; r < 4; ++r) {
      float d8[H_], ssum = 0.f, ssq = 0.f;
      #pragma unroll
      for (int h = 0; h < H_; ++h) {
        float s = s4[h][r] * scale;
        d8[h] = s; ssum += s; ssq += s * s;
      }
      float mu = ssum * 0.125f;
      float var = ssq * 0.125f - mu * mu;
      float rstd = rsqrtf(var + 1e-5f);
      float val = bias0;
      #pragma unroll
      for (int h = 0; h < H_; ++h)
        val += ((d8[h] - mu) * rstd * wsn[h] + bsn[h]) * wsf[h];
      stmp[((size_t)(b * M_) + rt * 64 + w * 16 + quad * 4 + r) * M_ + ct * 64 + cf * 16 + l16] = val;
    }
  }
}

// ---------------- s head stage 2: symmetrize out = 0.5*(s + s^T), tile-wise ----------------
__global__ __launch_bounds__(256) void k_sym(const float* __restrict__ stmp,
    float* __restrict__ outs)
{
  int ct = blockIdx.x, rt = blockIdx.y, b = blockIdx.z;
  __shared__ float Tb[64][68];
  int t = threadIdx.x;
  int row = t >> 2, seg = (t & 3) * 16;
  // load tile (ct,rt) rows, scatter transposed into Tb: Tb[i][j] = stmp[ct*64+j][rt*64+i]
  const float* srcB = stmp + ((size_t)(b * M_) + ct * 64 + row) * M_ + rt * 64 + seg;
  #pragma unroll
  for (int i = 0; i < 16; i += 4) {
    float4 v = *(const float4*)(srcB + i);
    Tb[seg + i + 0][row] = v.x;
    Tb[seg + i + 1][row] = v.y;
    Tb[seg + i + 2][row] = v.z;
    Tb[seg + i + 3][row] = v.w;
  }
  __syncthreads();
  const float* srcA = stmp + ((size_t)(b * M_) + rt * 64 + row) * M_ + ct * 64 + seg;
  float* dst = outs + ((size_t)(b * M_) + rt * 64 + row) * M_ + ct * 64 + seg;
  #pragma unroll
  for (int i = 0; i < 16; i += 4) {
    float4 a = *(const float4*)(srcA + i);
    float4 tv = *(const float4*)&Tb[row][seg + i];
    float4 o;
    o.x = 0.5f * (a.x + tv.x);
    o.y = 0.5f * (a.y + tv.y);
    o.z = 0.5f * (a.z + tv.z);
    o.w = 0.5f * (a.w + tv.w);
    *(float4*)(dst + i) = o;
  }
}

extern "C" void kernel_launch(void* const* d_in, const int* in_sizes, int n_in,
                              void* d_out, int out_size, void* d_ws, size_t ws_size,
                              hipStream_t stream)
{
  const float* X    = (const float*)d_in[0];
  const float* fW   = (const float*)d_in[2];
  const float* fb   = (const float*)d_in[3];
  const float* cW   = (const float*)d_in[4];
  const float* cb   = (const float*)d_in[5];
  const float* Wq   = (const float*)d_in[6];
  const float* bq   = (const float*)d_in[7];
  const float* Wk   = (const float*)d_in[8];
  const float* bk   = (const float*)d_in[9];
  const float* Wv   = (const float*)d_in[10];
  const float* bv   = (const float*)d_in[11];
  const float* Wo   = (const float*)d_in[12];
  const float* bo   = (const float*)d_in[13];
  const float* ln1w = (const float*)d_in[14];
  const float* ln1b = (const float*)d_in[15];
  const float* ln2w = (const float*)d_in[16];
  const float* ln2b = (const float*)d_in[17];
  const float* lnfw = (const float*)d_in[18];
  const float* lnfb = (const float*)d_in[19];
  const float* uw   = (const float*)d_in[20];
  const float* ub   = (const float*)d_in[21];
  const float* dw   = (const float*)d_in[22];
  const float* db   = (const float*)d_in[23];
  const float* finw = (const float*)d_in[24];
  const float* finb = (const float*)d_in[25];
  const float* snw  = (const float*)d_in[26];
  const float* snb  = (const float*)d_in[27];
  const float* sfw  = (const float*)d_in[28];
  const float* sfb  = (const float*)d_in[29];

  char* base = (char*)d_ws;
  const size_t MiB = 1024 * 1024;
  bf16* q_b   = (bf16*)(base + 0 * MiB);              // layer-3 q lives until s head
  bf16* k_b   = (bf16*)(base + 2 * MiB);              // layer-3 k lives until s head
  bf16* wqkvt = (bf16*)(base + 4 * MiB);              // 1.5 MiB: 4 layers x [768][256]
  bf16* wot   = (bf16*)(base + 5 * MiB + 512 * 1024); // 512 KiB
  bf16* uwt   = (bf16*)(base + 6 * MiB);              // 2 MiB
  bf16* dwt   = (bf16*)(base + 8 * MiB);              // 2 MiB
  bf16* fwt   = (bf16*)(base + 10 * MiB);             // 32 KiB
  float* x    = (float*)(base + 10 * MiB + 512 * 1024); // 4 MiB
  char* SR    = base + 14 * MiB + 512 * 1024;
  bf16* xn_b  = (bf16*)(SR + 0 * MiB);
  bf16* v_b   = (bf16*)(SR + 2 * MiB);
  bf16* att_b = (bf16*)(SR + 4 * MiB);
  bf16* h1_b  = (bf16*)(SR + 6 * MiB);                // 8 MiB
  float* stmp = (float*)(base + 32 * MiB);            // 16 MiB raw s scores
  float* outx = (float*)d_out;
  float* outs = outx + (size_t)BM_TOT * 64;

  dim3 blk(256);
  wconv_all<<<dim3(772), blk, 0, stream>>>(Wq, Wk, Wv, Wo, uw, dw, finw,
                                           wqkvt, wot, uwt, dwt, fwt);
  k_embed<<<dim3(BM_TOT / 4), blk, 0, stream>>>(X, fW, fb, cW, cb, x);
  for (int l = 0; l < L_; ++l) {
    k_ln<<<dim3(BM_TOT / 4), blk, 0, stream>>>(x, ln1w + l * D_, ln1b + l * D_, xn_b);
    mgemm_qkv<<<dim3(12, 64), blk, 0, stream>>>(xn_b, wqkvt + (size_t)l * 196608,
                                                bq + l * D_, bk + l * D_, bv + l * D_,
                                                q_b, k_b, v_b);
    k_flash<<<dim3(16, H_, B_), blk, 0, stream>>>(q_b, k_b, v_b, att_b);
    mgemm<<<dim3(4, 64), blk, 0, stream>>>(att_b, wot + (size_t)l * 65536, bo + l * D_,
                                           x, x, nullptr, 256, 256, 2 | 8);
    k_ln<<<dim3(BM_TOT / 4), blk, 0, stream>>>(x, ln2w + l * D_, ln2b + l * D_, xn_b);
    mgemm<<<dim3(16, 64), blk, 0, stream>>>(xn_b, uwt + (size_t)l * 262144, ub + l * DFF_,
                                            nullptr, nullptr, h1_b, 256, 1024, 1 | 4);
    mgemm<<<dim3(4, 64), blk, 0, stream>>>(h1_b, dwt + (size_t)l * 262144, db + l * D_,
                                           x, x, nullptr, 1024, 256, 2 | 8);
  }
  k_ln<<<dim3(BM_TOT / 4), blk, 0, stream>>>(x, lnfw, lnfb, xn_b);
  mgemm<<<dim3(1, 64), blk, 0, stream>>>(xn_b, fwt, finb, nullptr, outx, nullptr, 256, 64, 8);
  // layer-3 q/k still live in q_b/k_b
  k_shead1<<<dim3(16, 16, B_), blk, 0, stream>>>(q_b, k_b, snw, snb, sfw, sfb, stmp);
  k_sym<<<dim3(16, 16, B_), blk, 0, stream>>>(stmp, outs);
}

// Round 5
// 462.107 us; speedup vs baseline: 1.4176x; 1.0619x over previous
//
#include <hip/hip_runtime.h>
#include <hip/hip_bf16.h>
#include <math.h>

#define B_ 4
#define M_ 1024
#define NIN 70
#define D_ 256
#define H_ 8
#define L_ 4
#define DFF_ 1024
#define BM_TOT 4096

typedef __hip_bfloat16 bf16;
typedef short short8 __attribute__((ext_vector_type(8)));
typedef float f32x4 __attribute__((ext_vector_type(4)));

// ---------------- single-launch weight convert+transpose ----------------
__global__ __launch_bounds__(256) void wconv_all(
    const float* __restrict__ Wq, const float* __restrict__ Wk, const float* __restrict__ Wv,
    const float* __restrict__ Wo, const float* __restrict__ uw, const float* __restrict__ dw,
    const float* __restrict__ finw,
    bf16* __restrict__ wqkvt, bf16* __restrict__ wot, bf16* __restrict__ uwt,
    bf16* __restrict__ dwt, bf16* __restrict__ fwt)
{
  __shared__ float T[64][65];
  int idx = blockIdx.x;
  const float* src; bf16* dst; int K, N, k0, n0, rbase, S;
  if (idx < 192) {            // Wq/Wk/Wv -> wqkvt[l][m*256 + n][k]
    int m = idx >> 6; int r = idx & 63; int l = r >> 4; int tt = r & 15;
    int kt = tt >> 2, nt = tt & 3;
    src = (m == 0 ? Wq : (m == 1 ? Wk : Wv)) + (size_t)l * 65536;
    K = 256; N = 256; k0 = kt * 64; n0 = nt * 64;
    dst = wqkvt + (size_t)l * 196608; rbase = m * 256 + nt * 64; S = 256;
  } else if (idx < 256) {     // Wo
    int r = idx - 192; int l = r >> 4; int tt = r & 15; int kt = tt >> 2, nt = tt & 3;
    src = Wo + (size_t)l * 65536; K = 256; N = 256; k0 = kt * 64; n0 = nt * 64;
    dst = wot + (size_t)l * 65536; rbase = nt * 64; S = 256;
  } else if (idx < 512) {     // uw (256 x 1024)
    int r = idx - 256; int l = r >> 6; int tt = r & 63; int kt = tt >> 4, nt = tt & 15;
    src = uw + (size_t)l * 262144; K = 256; N = 1024; k0 = kt * 64; n0 = nt * 64;
    dst = uwt + (size_t)l * 262144; rbase = nt * 64; S = 256;
  } else if (idx < 768) {     // dw (1024 x 256)
    int r = idx - 512; int l = r >> 6; int tt = r & 63; int kt = tt >> 2, nt = tt & 3;
    src = dw + (size_t)l * 262144; K = 1024; N = 256; k0 = kt * 64; n0 = nt * 64;
    dst = dwt + (size_t)l * 262144; rbase = nt * 64; S = 1024;
  } else {                    // finw (256 x 64)
    int kt = idx - 768;
    src = finw; K = 256; N = 64; k0 = kt * 64; n0 = 0;
    dst = fwt; rbase = 0; S = 256;
  }
  int t = threadIdx.x;
  int kl = t >> 2, ns = (t & 3) * 16;
  #pragma unroll
  for (int i = 0; i < 16; i += 4)
    *(float4*)&T[kl][ns + i] = *(const float4*)&src[(size_t)(k0 + kl) * N + n0 + ns + i];
  __syncthreads();
  int nl = t >> 2, ks = (t & 3) * 16;
  __align__(16) bf16 tmp[16];
  #pragma unroll
  for (int i = 0; i < 16; ++i) tmp[i] = __float2bfloat16(T[ks + i][nl]);
  *(uint4*)&dst[(size_t)(rbase + nl) * S + k0 + ks] = *(uint4*)&tmp[0];
  *(uint4*)&dst[(size_t)(rbase + nl) * S + k0 + ks + 8] = *(uint4*)&tmp[8];
}

// ---------------- embedding: 4 rows/block ----------------
__global__ __launch_bounds__(256) void k_embed(const float* __restrict__ X,
    const float* __restrict__ fW, const float* __restrict__ fb,
    const float* __restrict__ cW, const float* __restrict__ cb,
    float* __restrict__ x)
{
  int bm0 = blockIdx.x * 4;
  int d = threadIdx.x;
  __shared__ float xr[4][NIN];
  for (int i = d; i < 4 * NIN; i += 256)
    xr[i / NIN][i % NIN] = X[(size_t)(bm0 + i / NIN) * NIN + i % NIN];
  __syncthreads();
  int f = d & 127;
  float fw0 = fW[f * 3 + 0], fw1 = fW[f * 3 + 1], fw2 = fW[f * 3 + 2], fbv = fb[f];
  float cbv = cb[d];
  float acc[4];
  #pragma unroll
  for (int r = 0; r < 4; ++r) {
    float proj = xr[r][0] * fw0 + xr[r][1] * fw1 + xr[r][2] * fw2 + fbv;
    acc[r] = (d < 128 ? cosf(proj) : sinf(proj)) * 0.17677669529663687f + cbv;
  }
  #pragma unroll 8
  for (int c = 0; c < 64; ++c) {
    float cw = cW[c * D_ + d];
    #pragma unroll
    for (int r = 0; r < 4; ++r) acc[r] += xr[r][6 + c] * cw;
  }
  #pragma unroll
  for (int r = 0; r < 4; ++r)
    x[(size_t)(bm0 + r) * D_ + d] = acc[r];
}

// ---------------- layernorm: fp32 in -> bf16 out ----------------
__global__ __launch_bounds__(256) void k_ln(const float* __restrict__ xin,
    const float* __restrict__ w, const float* __restrict__ b, bf16* __restrict__ xout)
{
  int wave = threadIdx.x >> 6;
  int lane = threadIdx.x & 63;
  int row = blockIdx.x * 4 + wave;
  float4 xv = *(const float4*)&xin[row * D_ + lane * 4];
  float s = xv.x + xv.y + xv.z + xv.w;
  float q = xv.x * xv.x + xv.y * xv.y + xv.z * xv.z + xv.w * xv.w;
  #pragma unroll
  for (int off = 32; off; off >>= 1) {
    s += __shfl_xor(s, off, 64);
    q += __shfl_xor(q, off, 64);
  }
  float mu = s * (1.0f / D_);
  float var = q * (1.0f / D_) - mu * mu;
  float rstd = rsqrtf(var + 1e-5f);
  float4 wv = *(const float4*)&w[lane * 4];
  float4 bv = *(const float4*)&b[lane * 4];
  __align__(8) bf16 tmp[4];
  tmp[0] = __float2bfloat16((xv.x - mu) * rstd * wv.x + bv.x);
  tmp[1] = __float2bfloat16((xv.y - mu) * rstd * wv.y + bv.y);
  tmp[2] = __float2bfloat16((xv.z - mu) * rstd * wv.z + bv.z);
  tmp[3] = __float2bfloat16((xv.w - mu) * rstd * wv.w + bv.w);
  *(uint2*)&xout[row * D_ + lane * 4] = *(uint2*)tmp;
}

// ---------------- MFMA GEMM (reg-prefetch, 256 thr; used for uw) ----------------
__global__ __launch_bounds__(256) void mgemm(const bf16* __restrict__ Ab,
    const bf16* __restrict__ Wt, const float* __restrict__ bias,
    const float* __restrict__ Res, float* __restrict__ Cf, bf16* __restrict__ Cb,
    int K, int N, int flags)
{
  __shared__ short As[64][40];
  __shared__ short Bs[64][40];
  int t = threadIdx.x;
  int m0 = blockIdx.y * 64, n0 = blockIdx.x * 64;
  int w = t >> 6, lane = t & 63;
  int srow = t >> 2, sseg = t & 3;
  f32x4 acc[4] = {{0.f,0.f,0.f,0.f},{0.f,0.f,0.f,0.f},{0.f,0.f,0.f,0.f},{0.f,0.f,0.f,0.f}};
  int mf = w * 16 + (lane & 15);
  int kf = (lane >> 4) * 8;
  const bf16* pA = Ab + (size_t)(m0 + srow) * K + sseg * 8;
  const bf16* pB = Wt + (size_t)(n0 + srow) * K + sseg * 8;
  uint4 ra = *(const uint4*)pA;
  uint4 rb = *(const uint4*)pB;
  for (int k0 = 0; k0 < K; k0 += 32) {
    *(uint4*)&As[srow][sseg * 8] = ra;
    *(uint4*)&Bs[srow][sseg * 8] = rb;
    __syncthreads();
    if (k0 + 32 < K) {
      ra = *(const uint4*)(pA + k0 + 32);
      rb = *(const uint4*)(pB + k0 + 32);
    }
    short8 a = *(short8*)&As[mf][kf];
    #pragma unroll
    for (int nt = 0; nt < 4; ++nt) {
      short8 bfr = *(short8*)&Bs[nt * 16 + (lane & 15)][kf];
      acc[nt] = __builtin_amdgcn_mfma_f32_16x16x32_bf16(a, bfr, acc[nt], 0, 0, 0);
    }
    __syncthreads();
  }
  int row0 = m0 + w * 16 + (lane >> 4) * 4;
  #pragma unroll
  for (int nt = 0; nt < 4; ++nt) {
    int col = n0 + nt * 16 + (lane & 15);
    float bs = bias[col];
    #pragma unroll
    for (int r = 0; r < 4; ++r) {
      float v = acc[nt][r] + bs;
      if (flags & 1) v = 0.5f * v * (1.0f + erff(v * 0.70710678118654752f));
      if (flags & 2) v += Res[(size_t)(row0 + r) * N + col];
      if (flags & 8) Cf[(size_t)(row0 + r) * N + col] = v;
      if (flags & 4) Cb[(size_t)(row0 + r) * N + col] = __float2bfloat16(v);
    }
  }
}

// ---------------- MFMA GEMM, 512 threads / 8 waves per 64x64 tile ----------------
// Same tile + identical accumulation/epilogue arithmetic as mgemm, but 8 waves:
// wave w computes rows (w&3)*16, col-frags {(w>>2)*2, (w>>2)*2+1}. Threads 0-255
// stage As, 256-511 stage Bs (1 uint4 each, reg-prefetched). Doubles resident
// waves/CU for small grids (wo/dw at 256 blocks were BW-starved at 4 waves/CU).
__global__ __launch_bounds__(512) void mgemm512(const bf16* __restrict__ Ab,
    const bf16* __restrict__ Wt, const float* __restrict__ bias,
    const float* __restrict__ Res, float* __restrict__ Cf, bf16* __restrict__ Cb,
    int K, int N, int flags)
{
  __shared__ short As[64][40];
  __shared__ short Bs[64][40];
  int t = threadIdx.x;
  int m0 = blockIdx.y * 64, n0 = blockIdx.x * 64;
  int w = t >> 6, lane = t & 63;
  int l16 = lane & 15, quad = lane >> 4;
  int s = t & 255;
  int srow = s >> 2, sseg = s & 3;
  bool isA = (t < 256);
  short (*S)[40] = isA ? As : Bs;
  const bf16* pS = (isA ? Ab + (size_t)(m0 + srow) * K
                        : Wt + (size_t)(n0 + srow) * K) + sseg * 8;
  uint4 ra = *(const uint4*)pS;
  f32x4 acc[2] = {{0.f,0.f,0.f,0.f},{0.f,0.f,0.f,0.f}};
  int mf = (w & 3) * 16 + l16;
  int kf = quad * 8;
  int ntb = (w >> 2) * 2;
  for (int k0 = 0; k0 < K; k0 += 32) {
    *(uint4*)&S[srow][sseg * 8] = ra;
    __syncthreads();
    if (k0 + 32 < K) ra = *(const uint4*)(pS + k0 + 32);
    short8 a = *(short8*)&As[mf][kf];
    #pragma unroll
    for (int i = 0; i < 2; ++i) {
      short8 bfr = *(short8*)&Bs[(ntb + i) * 16 + l16][kf];
      acc[i] = __builtin_amdgcn_mfma_f32_16x16x32_bf16(a, bfr, acc[i], 0, 0, 0);
    }
    __syncthreads();
  }
  int row0 = m0 + (w & 3) * 16 + quad * 4;
  #pragma unroll
  for (int i = 0; i < 2; ++i) {
    int col = n0 + (ntb + i) * 16 + l16;
    float bs = bias[col];
    #pragma unroll
    for (int r = 0; r < 4; ++r) {
      float v = acc[i][r] + bs;
      if (flags & 1) v = 0.5f * v * (1.0f + erff(v * 0.70710678118654752f));
      if (flags & 2) v += Res[(size_t)(row0 + r) * N + col];
      if (flags & 8) Cf[(size_t)(row0 + r) * N + col] = v;
      if (flags & 4) Cb[(size_t)(row0 + r) * N + col] = __float2bfloat16(v);
    }
  }
}

// ---------------- fused QKV MFMA GEMM (reg-prefetch, unchanged) ----------------
__global__ __launch_bounds__(256) void mgemm_qkv(const bf16* __restrict__ Ab,
    const bf16* __restrict__ Wt, const float* __restrict__ bq,
    const float* __restrict__ bk, const float* __restrict__ bv,
    bf16* __restrict__ qo, bf16* __restrict__ ko, bf16* __restrict__ vo)
{
  __shared__ short As[64][40];
  __shared__ short Bs[64][40];
  int t = threadIdx.x;
  int m0 = blockIdx.y * 64, n0g = blockIdx.x * 64;
  int w = t >> 6, lane = t & 63;
  int srow = t >> 2, sseg = t & 3;
  f32x4 acc[4] = {{0.f,0.f,0.f,0.f},{0.f,0.f,0.f,0.f},{0.f,0.f,0.f,0.f},{0.f,0.f,0.f,0.f}};
  int mf = w * 16 + (lane & 15);
  int kf = (lane >> 4) * 8;
  const bf16* pA = Ab + (size_t)(m0 + srow) * 256 + sseg * 8;
  const bf16* pB = Wt + (size_t)(n0g + srow) * 256 + sseg * 8;
  uint4 ra = *(const uint4*)pA;
  uint4 rb = *(const uint4*)pB;
  for (int k0 = 0; k0 < 256; k0 += 32) {
    *(uint4*)&As[srow][sseg * 8] = ra;
    *(uint4*)&Bs[srow][sseg * 8] = rb;
    __syncthreads();
    if (k0 + 32 < 256) {
      ra = *(const uint4*)(pA + k0 + 32);
      rb = *(const uint4*)(pB + k0 + 32);
    }
    short8 a = *(short8*)&As[mf][kf];
    #pragma unroll
    for (int nt = 0; nt < 4; ++nt) {
      short8 bfr = *(short8*)&Bs[nt * 16 + (lane & 15)][kf];
      acc[nt] = __builtin_amdgcn_mfma_f32_16x16x32_bf16(a, bfr, acc[nt], 0, 0, 0);
    }
    __syncthreads();
  }
  int seg = n0g >> 8;
  const float* bb = (seg == 0 ? bq : (seg == 1 ? bk : bv));
  bf16* dst = (seg == 0 ? qo : (seg == 1 ? ko : vo));
  int row0 = m0 + w * 16 + (lane >> 4) * 4;
  #pragma unroll
  for (int nt = 0; nt < 4; ++nt) {
    int col = (n0g & 255) + nt * 16 + (lane & 15);
    float bs = bb[col];
    #pragma unroll
    for (int r = 0; r < 4; ++r)
      dst[(size_t)(row0 + r) * 256 + col] = __float2bfloat16(acc[nt][r] + bs);
  }
}

// ---------------- MFMA flash attention (unchanged) ----------------
__global__ __launch_bounds__(256) void k_flash(const bf16* __restrict__ q,
    const bf16* __restrict__ k, const bf16* __restrict__ v, bf16* __restrict__ o)
{
  int qt = blockIdx.x, h = blockIdx.y, b = blockIdx.z;
  int t = threadIdx.x;
  int w = t >> 6, lane = t & 63;
  int quad = lane >> 4, l16 = lane & 15;
  __shared__ short Ks[64][40];
  __shared__ short Vt[32][76];
  __shared__ short Pl[4][16][72];
  short8 a_q = *(const short8*)&q[((size_t)(b * M_) + qt * 64 + w * 16 + l16) * D_ + h * 32 + quad * 8];
  f32x4 o_acc[2] = {{0.f,0.f,0.f,0.f},{0.f,0.f,0.f,0.f}};
  float l_acc[4] = {0.f, 0.f, 0.f, 0.f};
  int skey = t >> 2, sseg = t & 3;
  const float scale = 0.17677669529663687f;
  for (int kt = 0; kt < 16; ++kt) {
    __syncthreads();
    *(short8*)&Ks[skey][sseg * 8] =
        *(const short8*)&k[((size_t)(b * M_) + kt * 64 + skey) * D_ + h * 32 + sseg * 8];
    short8 vv = *(const short8*)&v[((size_t)(b * M_) + kt * 64 + skey) * D_ + h * 32 + sseg * 8];
    #pragma unroll
    for (int i = 0; i < 8; ++i) Vt[sseg * 8 + i][skey] = vv[i];
    __syncthreads();
    #pragma unroll
    for (int st = 0; st < 4; ++st) {
      short8 bf = *(short8*)&Ks[st * 16 + l16][quad * 8];
      f32x4 s4 = __builtin_amdgcn_mfma_f32_16x16x32_bf16(a_q, bf, (f32x4){0.f,0.f,0.f,0.f}, 0, 0, 0);
      #pragma unroll
      for (int r = 0; r < 4; ++r) {
        float p = __expf(s4[r] * scale);
        l_acc[r] += p;
        bf16 hb = __float2bfloat16(p);
        Pl[w][quad * 4 + r][st * 16 + l16] = *reinterpret_cast<short*>(&hb);
      }
    }
    asm volatile("s_waitcnt lgkmcnt(0)" ::: "memory");
    #pragma unroll
    for (int kh = 0; kh < 2; ++kh) {
      short8 a_p = *(short8*)&Pl[w][l16][kh * 32 + quad * 8];
      #pragma unroll
      for (int nt = 0; nt < 2; ++nt) {
        short8 b_v = *(short8*)&Vt[nt * 16 + l16][kh * 32 + quad * 8];
        o_acc[nt] = __builtin_amdgcn_mfma_f32_16x16x32_bf16(a_p, b_v, o_acc[nt], 0, 0, 0);
      }
    }
  }
  #pragma unroll
  for (int r = 0; r < 4; ++r) {
    float lv = l_acc[r];
    lv += __shfl_xor(lv, 1, 64);
    lv += __shfl_xor(lv, 2, 64);
    lv += __shfl_xor(lv, 4, 64);
    lv += __shfl_xor(lv, 8, 64);
    l_acc[r] = 1.0f / lv;
  }
  #pragma unroll
  for (int nt = 0; nt < 2; ++nt)
    #pragma unroll
    for (int r = 0; r < 4; ++r)
      o[((size_t)(b * M_) + qt * 64 + w * 16 + quad * 4 + r) * D_ + h * 32 + nt * 16 + l16] =
          __float2bfloat16(o_acc[nt][r] * l_acc[r]);
}

// ---------------- s head stage 1 (unchanged) ----------------
__global__ __launch_bounds__(256) void k_shead1(const bf16* __restrict__ q3,
    const bf16* __restrict__ k3, const float* __restrict__ snw, const float* __restrict__ snb,
    const float* __restrict__ sfw, const float* __restrict__ sfb, float* __restrict__ stmp)
{
  int ct = blockIdx.x, rt = blockIdx.y, b = blockIdx.z;
  int t = threadIdx.x;
  int w = t >> 6, lane = t & 63;
  int quad = lane >> 4, l16 = lane & 15;
  const float scale = 0.17677669529663687f;
  float wsn[H_], bsn[H_], wsf[H_];
  #pragma unroll
  for (int h = 0; h < H_; ++h) { wsn[h] = snw[h]; bsn[h] = snb[h]; wsf[h] = sfw[h]; }
  float bias0 = sfb[0];
  short8 aqs[H_];
  #pragma unroll
  for (int h = 0; h < H_; ++h)
    aqs[h] = *(const short8*)&q3[((size_t)(b * M_) + rt * 64 + w * 16 + l16) * D_ + h * 32 + quad * 8];
  #pragma unroll
  for (int cf = 0; cf < 4; ++cf) {
    f32x4 s4[H_];
    #pragma unroll
    for (int h = 0; h < H_; ++h) {
      short8 bk = *(const short8*)&k3[((size_t)(b * M_) + ct * 64 + cf * 16 + l16) * D_ + h * 32 + quad * 8];
      s4[h] = __builtin_amdgcn_mfma_f32_16x16x32_bf16(aqs[h], bk, (f32x4){0.f,0.f,0.f,0.f}, 0, 0, 0);
    }
    #pragma unroll
    for (int r = 0; r < 4; ++r) {
      float d8[H_], ssum = 0.f, ssq = 0.f;
      #pragma unroll
      for (int h = 0; h < H_; ++h) {
        float s = s4[h][r] * scale;
        d8[h] = s; ssum += s; ssq += s * s;
      }
      float mu = ssum * 0.125f;
      float var = ssq * 0.125f - mu * mu;
      float rstd = rsqrtf(var + 1e-5f);
      float val = bias0;
      #pragma unroll
      for (int h = 0; h < H_; ++h)
        val += ((d8[h] - mu) * rstd * wsn[h] + bsn[h]) * wsf[h];
      stmp[((size_t)(b * M_) + rt * 64 + w * 16 + quad * 4 + r) * M_ + ct * 64 + cf * 16 + l16] = val;
    }
  }
}

// ---------------- s head stage 2: symmetrize (unchanged) ----------------
__global__ __launch_bounds__(256) void k_sym(const float* __restrict__ stmp,
    float* __restrict__ outs)
{
  int ct = blockIdx.x, rt = blockIdx.y, b = blockIdx.z;
  __shared__ float Tb[64][68];
  int t = threadIdx.x;
  int row = t >> 2, seg = (t & 3) * 16;
  const float* srcB = stmp + ((size_t)(b * M_) + ct * 64 + row) * M_ + rt * 64 + seg;
  #pragma unroll
  for (int i = 0; i < 16; i += 4) {
    float4 v = *(const float4*)(srcB + i);
    Tb[seg + i + 0][row] = v.x;
    Tb[seg + i + 1][row] = v.y;
    Tb[seg + i + 2][row] = v.z;
    Tb[seg + i + 3][row] = v.w;
  }
  __syncthreads();
  const float* srcA = stmp + ((size_t)(b * M_) + rt * 64 + row) * M_ + ct * 64 + seg;
  float* dst = outs + ((size_t)(b * M_) + rt * 64 + row) * M_ + ct * 64 + seg;
  #pragma unroll
  for (int i = 0; i < 16; i += 4) {
    float4 a = *(const float4*)(srcA + i);
    float4 tv = *(const float4*)&Tb[row][seg + i];
    float4 o;
    o.x = 0.5f * (a.x + tv.x);
    o.y = 0.5f * (a.y + tv.y);
    o.z = 0.5f * (a.z + tv.z);
    o.w = 0.5f * (a.w + tv.w);
    *(float4*)(dst + i) = o;
  }
}

extern "C" void kernel_launch(void* const* d_in, const int* in_sizes, int n_in,
                              void* d_out, int out_size, void* d_ws, size_t ws_size,
                              hipStream_t stream)
{
  const float* X    = (const float*)d_in[0];
  const float* fW   = (const float*)d_in[2];
  const float* fb   = (const float*)d_in[3];
  const float* cW   = (const float*)d_in[4];
  const float* cb   = (const float*)d_in[5];
  const float* Wq   = (const float*)d_in[6];
  const float* bq   = (const float*)d_in[7];
  const float* Wk   = (const float*)d_in[8];
  const float* bk   = (const float*)d_in[9];
  const float* Wv   = (const float*)d_in[10];
  const float* bv   = (const float*)d_in[11];
  const float* Wo   = (const float*)d_in[12];
  const float* bo   = (const float*)d_in[13];
  const float* ln1w = (const float*)d_in[14];
  const float* ln1b = (const float*)d_in[15];
  const float* ln2w = (const float*)d_in[16];
  const float* ln2b = (const float*)d_in[17];
  const float* lnfw = (const float*)d_in[18];
  const float* lnfb = (const float*)d_in[19];
  const float* uw   = (const float*)d_in[20];
  const float* ub   = (const float*)d_in[21];
  const float* dw   = (const float*)d_in[22];
  const float* db   = (const float*)d_in[23];
  const float* finw = (const float*)d_in[24];
  const float* finb = (const float*)d_in[25];
  const float* snw  = (const float*)d_in[26];
  const float* snb  = (const float*)d_in[27];
  const float* sfw  = (const float*)d_in[28];
  const float* sfb  = (const float*)d_in[29];

  char* base = (char*)d_ws;
  const size_t MiB = 1024 * 1024;
  bf16* q_b   = (bf16*)(base + 0 * MiB);              // layer-3 q lives until s head
  bf16* k_b   = (bf16*)(base + 2 * MiB);              // layer-3 k lives until s head
  bf16* wqkvt = (bf16*)(base + 4 * MiB);              // 1.5 MiB: 4 layers x [768][256]
  bf16* wot   = (bf16*)(base + 5 * MiB + 512 * 1024); // 512 KiB
  bf16* uwt   = (bf16*)(base + 6 * MiB);              // 2 MiB
  bf16* dwt   = (bf16*)(base + 8 * MiB);              // 2 MiB
  bf16* fwt   = (bf16*)(base + 10 * MiB);             // 32 KiB
  float* x    = (float*)(base + 10 * MiB + 512 * 1024); // 4 MiB
  char* SR    = base + 14 * MiB + 512 * 1024;
  bf16* xn_b  = (bf16*)(SR + 0 * MiB);
  bf16* v_b   = (bf16*)(SR + 2 * MiB);
  bf16* att_b = (bf16*)(SR + 4 * MiB);
  bf16* h1_b  = (bf16*)(SR + 6 * MiB);                // 8 MiB
  float* stmp = (float*)(base + 32 * MiB);            // 16 MiB raw s scores
  float* outx = (float*)d_out;
  float* outs = outx + (size_t)BM_TOT * 64;

  dim3 blk(256);
  dim3 blk512(512);
  wconv_all<<<dim3(772), blk, 0, stream>>>(Wq, Wk, Wv, Wo, uw, dw, finw,
                                           wqkvt, wot, uwt, dwt, fwt);
  k_embed<<<dim3(BM_TOT / 4), blk, 0, stream>>>(X, fW, fb, cW, cb, x);
  for (int l = 0; l < L_; ++l) {
    k_ln<<<dim3(BM_TOT / 4), blk, 0, stream>>>(x, ln1w + l * D_, ln1b + l * D_, xn_b);
    mgemm_qkv<<<dim3(12, 64), blk, 0, stream>>>(xn_b, wqkvt + (size_t)l * 196608,
                                                bq + l * D_, bk + l * D_, bv + l * D_,
                                                q_b, k_b, v_b);
    k_flash<<<dim3(16, H_, B_), blk, 0, stream>>>(q_b, k_b, v_b, att_b);
    mgemm512<<<dim3(4, 64), blk512, 0, stream>>>(att_b, wot + (size_t)l * 65536, bo + l * D_,
                                                 x, x, nullptr, 256, 256, 2 | 8);
    k_ln<<<dim3(BM_TOT / 4), blk, 0, stream>>>(x, ln2w + l * D_, ln2b + l * D_, xn_b);
    mgemm<<<dim3(16, 64), blk, 0, stream>>>(xn_b, uwt + (size_t)l * 262144, ub + l * DFF_,
                                            nullptr, nullptr, h1_b, 256, 1024, 1 | 4);
    mgemm512<<<dim3(4, 64), blk512, 0, stream>>>(h1_b, dwt + (size_t)l * 262144, db + l * D_,
                                                 x, x, nullptr, 1024, 256, 2 | 8);
  }
  k_ln<<<dim3(BM_TOT / 4), blk, 0, stream>>>(x, lnfw, lnfb, xn_b);
  mgemm512<<<dim3(1, 64), blk512, 0, stream>>>(xn_b, fwt, finb, nullptr, outx, nullptr, 256, 64, 8);
  // layer-3 q/k still live in q_b/k_b
  k_shead1<<<dim3(16, 16, B_), blk, 0, stream>>>(q_b, k_b, snw, snb, sfw, sfb, stmp);
  k_sym<<<dim3(16, 16, B_), blk, 0, stream>>>(stmp, outs);
}